// Round 2
// baseline (5024.438 us; speedup 1.0000x reference)
//
#include <hip/hip_runtime.h>
#include <hip/hip_bf16.h>

#define B_  2
#define T_  2048
#define NH_ 16
#define HS_ 64
#define C_  1024
#define EXP_SCALE_ 10.0f
#define KB_UP_ 5.0f

// ---------------------------------------------------------------------------
// GEMM: C[M,N] = A[M,K] @ W[K,N]. All fp32. 64x64 tile, BK=16, 256 thr,
// 4x4 microtile per thread.
// ---------------------------------------------------------------------------
__global__ __launch_bounds__(256) void gemm_aw(const float* __restrict__ A,
                                               const float* __restrict__ W,
                                               float* __restrict__ Cout,
                                               int M, int N, int K) {
  __shared__ float As[16][68];  // [k][m]; 68*4=272B rows stay 16B-aligned, break pow2 stride
  __shared__ float Bs[16][68];  // [k][n]
  const int tid = threadIdx.x;
  const int tx = tid & 15;
  const int ty = tid >> 4;
  const int m0 = blockIdx.y * 64;
  const int n0 = blockIdx.x * 64;

  const int ar = tid >> 2;        // 0..63 : A-tile row
  const int ak = (tid & 3) * 4;   // 0,4,8,12 : A-tile k start
  const int wkk = tid >> 4;       // 0..15 : W-tile k row
  const int wn = (tid & 15) * 4;  // 0..60 : W-tile n start

  float acc[4][4] = {};

  for (int k0 = 0; k0 < K; k0 += 16) {
    {
      const float4 a4 = *reinterpret_cast<const float4*>(A + (size_t)(m0 + ar) * K + k0 + ak);
      As[ak + 0][ar] = a4.x;
      As[ak + 1][ar] = a4.y;
      As[ak + 2][ar] = a4.z;
      As[ak + 3][ar] = a4.w;
    }
    {
      const float4 w4 = *reinterpret_cast<const float4*>(W + (size_t)(k0 + wkk) * N + n0 + wn);
      *reinterpret_cast<float4*>(&Bs[wkk][wn]) = w4;
    }
    __syncthreads();
#pragma unroll
    for (int kk = 0; kk < 16; ++kk) {
      float4 a4 = *reinterpret_cast<const float4*>(&As[kk][ty * 4]);
      float4 b4 = *reinterpret_cast<const float4*>(&Bs[kk][tx * 4]);
      float a[4] = {a4.x, a4.y, a4.z, a4.w};
      float b[4] = {b4.x, b4.y, b4.z, b4.w};
#pragma unroll
      for (int i = 0; i < 4; ++i)
#pragma unroll
        for (int j = 0; j < 4; ++j) acc[i][j] += a[i] * b[j];
    }
    __syncthreads();
  }

#pragma unroll
  for (int i = 0; i < 4; ++i) {
    const int m = m0 + ty * 4 + i;
#pragma unroll
    for (int j = 0; j < 4; ++j) {
      const int n = n0 + tx * 4 + j;
      Cout[(size_t)m * N + n] = acc[i][j];
    }
  }
}

// ---------------------------------------------------------------------------
// EMA scan over time. One block per (b,h). 256 threads stage 256 timesteps of
// xl[b, t, h, :] into LDS; lanes 0..63 then run the sequential recurrence.
// Output k in (B, NH, T, HS) layout (un-normalized).
// ---------------------------------------------------------------------------
#define CHUNK_ 256
__global__ __launch_bounds__(256) void ema_scan_kernel(const float* __restrict__ xl,
                                                       float* __restrict__ kout,
                                                       const float* __restrict__ la_coef) {
  const int bh = blockIdx.x;  // b*NH + h
  const int b = bh / NH_, h = bh % NH_;
  const int tid = threadIdx.x;
  __shared__ float buf[CHUNK_ * HS_];  // 64 KiB

  const float alpha = la_coef[h];
  const float onema = 1.0f - alpha;
  const float* src = xl + (size_t)b * T_ * C_ + h * HS_;
  float* dst = kout + (size_t)bh * T_ * HS_;

  float carry = 0.0f;
  for (int t0 = 0; t0 < T_; t0 += CHUNK_) {
#pragma unroll
    for (int i = 0; i < (CHUNK_ * HS_) / 256; ++i) {
      const int e = tid + i * 256;
      const int tt = e >> 6, d = e & 63;
      buf[e] = src[(size_t)(t0 + tt) * C_ + d];
    }
    __syncthreads();
    if (tid < 64) {
      const int d = tid;
      float c2 = carry;
#pragma unroll 8
      for (int tt = 0; tt < CHUNK_; ++tt) {
        c2 = alpha * c2 + onema * buf[tt * HS_ + d];
        dst[(size_t)(t0 + tt) * HS_ + d] = c2;
      }
      carry = c2;
    }
    __syncthreads();
  }
}

// ---------------------------------------------------------------------------
// Normalize k rows and scale by kb = exp(min(kernel_beta*ES, KB_UP)).
// One wave per (b,h,t) row of 64. Block = 4 waves.
// ---------------------------------------------------------------------------
__global__ __launch_bounds__(256) void knorm_kernel(float* __restrict__ k,
                                                    const float* __restrict__ kernel_beta) {
  const int row = blockIdx.x * 4 + (threadIdx.x >> 6);
  const int lane = threadIdx.x & 63;
  const int h = (row / T_) % NH_;
  float val = k[(size_t)row * HS_ + lane];
  float ss = val * val;
#pragma unroll
  for (int m = 32; m; m >>= 1) ss += __shfl_xor(ss, m);
  const float kb = expf(fminf(kernel_beta[h] * EXP_SCALE_, KB_UP_));
  k[(size_t)row * HS_ + lane] = val * (kb / sqrtf(ss));
}

// ---------------------------------------------------------------------------
// Build v: v_t = xv[t+1]*(1-c) + xv[t]*c (t+1 OOR -> 0), normalize, scale by
// exp(value_beta*ES). xv is (B,T,NH,HS); v written (B,NH,T,HS).
// ---------------------------------------------------------------------------
__global__ __launch_bounds__(256) void vprep_kernel(const float* __restrict__ xv,
                                                    float* __restrict__ v,
                                                    const float* __restrict__ value_beta,
                                                    const float* __restrict__ v_coef) {
  const int row = blockIdx.x * 4 + (threadIdx.x >> 6);
  const int lane = threadIdx.x & 63;
  const int t = row % T_;
  const int bh = row / T_;
  const int h = bh % NH_;
  const int b = bh / NH_;
  const float* base = xv + (size_t)b * T_ * C_ + h * HS_ + lane;
  const float cur = base[(size_t)t * C_];
  const float nxt = (t + 1 < T_) ? base[(size_t)(t + 1) * C_] : 0.0f;
  const float c = v_coef[h];
  float val = nxt * (1.0f - c) + cur * c;
  float ss = val * val;
#pragma unroll
  for (int m = 32; m; m >>= 1) ss += __shfl_xor(ss, m);
  const float vb = expf(value_beta[h] * EXP_SCALE_);
  v[(size_t)row * HS_ + lane] = val * (vb / sqrtf(ss));
}

// ---------------------------------------------------------------------------
// Causal attention, one wave per query. q_t = k[b,h,tq,:], keys 0..tq-1.
// Scores bounded by kb^2 <= e^2 so exp() cannot overflow fp32 — no max pass.
// Output into y (B,T,NH,HS)=(B,T,C) layout; tq==0 row zeroed here.
// ---------------------------------------------------------------------------
__global__ __launch_bounds__(64) void attn_kernel(const float* __restrict__ k,
                                                  const float* __restrict__ v,
                                                  float* __restrict__ y) {
  const int idx = blockIdx.x;
  const int tq = idx % T_;
  const int bh = idx / T_;
  const int b = bh / NH_, h = bh % NH_;
  const int lane = threadIdx.x;
  float* yrow = y + (size_t)b * T_ * C_ + (size_t)tq * C_ + h * HS_ + lane;
  if (tq == 0) { *yrow = 0.0f; return; }

  const float* kb_ = k + (size_t)bh * T_ * HS_;
  const float* vb_ = v + (size_t)bh * T_ * HS_;
  const float q = kb_[(size_t)tq * HS_ + lane];
  float l = 0.0f, o = 0.0f;
#pragma unroll 4
  for (int j = 0; j < tq; ++j) {
    float s = q * kb_[(size_t)j * HS_ + lane];
#pragma unroll
    for (int m = 32; m; m >>= 1) s += __shfl_xor(s, m);
    const float p = __expf(s);
    l += p;
    o += p * vb_[(size_t)j * HS_ + lane];
  }
  *yrow = o / l;
}

// ---------------------------------------------------------------------------
extern "C" void kernel_launch(void* const* d_in, const int* in_sizes, int n_in,
                              void* d_out, int out_size, void* d_ws, size_t ws_size,
                              hipStream_t stream) {
  const float* x           = (const float*)d_in[0];
  const float* W_la        = (const float*)d_in[1];
  const float* la_coef     = (const float*)d_in[2];
  const float* kernel_beta = (const float*)d_in[3];
  const float* value_beta  = (const float*)d_in[4];
  const float* W_v         = (const float*)d_in[5];
  const float* v_coef      = (const float*)d_in[6];
  const float* W_proj      = (const float*)d_in[7];
  float* out = (float*)d_out;

  const size_t NELEM = (size_t)B_ * T_ * C_;  // 4 Mi elements
  float* ws = (float*)d_ws;
  float* xl   = ws;              // (B,T,C); reused as y after the scan consumes it
  float* xv   = ws + NELEM;      // (B,T,C)
  float* kbuf = ws + 2 * NELEM;  // (B,NH,T,HS)
  float* vbuf = ws + 3 * NELEM;  // (B,NH,T,HS)
  float* y = xl;

  const int M = B_ * T_;
  dim3 gg(C_ / 64, M / 64);

  gemm_aw<<<gg, dim3(256), 0, stream>>>(x, W_la, xl, M, C_, C_);
  gemm_aw<<<gg, dim3(256), 0, stream>>>(x, W_v, xv, M, C_, C_);
  ema_scan_kernel<<<dim3(B_ * NH_), dim3(256), 0, stream>>>(xl, kbuf, la_coef);
  knorm_kernel<<<dim3(B_ * NH_ * T_ / 4), dim3(256), 0, stream>>>(kbuf, kernel_beta);
  vprep_kernel<<<dim3(B_ * NH_ * T_ / 4), dim3(256), 0, stream>>>(xv, vbuf, value_beta, v_coef);
  attn_kernel<<<dim3(B_ * NH_ * T_), dim3(64), 0, stream>>>(kbuf, vbuf, y);
  gemm_aw<<<gg, dim3(256), 0, stream>>>(y, W_proj, out, M, C_, C_);
}

// Round 3
// 727.314 us; speedup vs baseline: 6.9082x; 6.9082x over previous
//
#include <hip/hip_runtime.h>
#include <hip/hip_bf16.h>

#define B_  2
#define T_  2048
#define NH_ 16
#define HS_ 64
#define C_  1024

typedef __attribute__((ext_vector_type(8))) short bf16x8;
typedef __attribute__((ext_vector_type(4))) float f32x4;

__device__ inline int pack_bf16(float a, float b) {
  union { __hip_bfloat16 h; unsigned short u; } ua, ub;
  ua.h = __float2bfloat16(a);
  ub.h = __float2bfloat16(b);
  return (int)(((unsigned)ub.u << 16) | (unsigned)ua.u);
}

// ---------------------------------------------------------------------------
// GEMM: C[M,N] = A[M,K] @ W[K,N]. All fp32. 64x64 tile, BK=16, 256 thr,
// 4x4 microtile per thread. (Round-2 baseline, unchanged.)
// ---------------------------------------------------------------------------
__global__ __launch_bounds__(256) void gemm_aw(const float* __restrict__ A,
                                               const float* __restrict__ W,
                                               float* __restrict__ Cout,
                                               int M, int N, int K) {
  __shared__ float As[16][68];
  __shared__ float Bs[16][68];
  const int tid = threadIdx.x;
  const int tx = tid & 15;
  const int ty = tid >> 4;
  const int m0 = blockIdx.y * 64;
  const int n0 = blockIdx.x * 64;

  const int ar = tid >> 2;
  const int ak = (tid & 3) * 4;
  const int wkk = tid >> 4;
  const int wn = (tid & 15) * 4;

  float acc[4][4] = {};

  for (int k0 = 0; k0 < K; k0 += 16) {
    {
      const float4 a4 = *reinterpret_cast<const float4*>(A + (size_t)(m0 + ar) * K + k0 + ak);
      As[ak + 0][ar] = a4.x;
      As[ak + 1][ar] = a4.y;
      As[ak + 2][ar] = a4.z;
      As[ak + 3][ar] = a4.w;
    }
    {
      const float4 w4 = *reinterpret_cast<const float4*>(W + (size_t)(k0 + wkk) * N + n0 + wn);
      *reinterpret_cast<float4*>(&Bs[wkk][wn]) = w4;
    }
    __syncthreads();
#pragma unroll
    for (int kk = 0; kk < 16; ++kk) {
      float4 a4 = *reinterpret_cast<const float4*>(&As[kk][ty * 4]);
      float4 b4 = *reinterpret_cast<const float4*>(&Bs[kk][tx * 4]);
      float a[4] = {a4.x, a4.y, a4.z, a4.w};
      float b[4] = {b4.x, b4.y, b4.z, b4.w};
#pragma unroll
      for (int i = 0; i < 4; ++i)
#pragma unroll
        for (int j = 0; j < 4; ++j) acc[i][j] += a[i] * b[j];
    }
    __syncthreads();
  }

#pragma unroll
  for (int i = 0; i < 4; ++i) {
    const int m = m0 + ty * 4 + i;
#pragma unroll
    for (int j = 0; j < 4; ++j) {
      const int n = n0 + tx * 4 + j;
      Cout[(size_t)m * N + n] = acc[i][j];
    }
  }
}

// ---------------------------------------------------------------------------
// EMA scan over time. One block per (b,h). Writes kscan fp32 (B,NH,T,HS).
// ---------------------------------------------------------------------------
#define CHUNK_ 256
__global__ __launch_bounds__(256) void ema_scan_kernel(const float* __restrict__ xl,
                                                       float* __restrict__ kout,
                                                       const float* __restrict__ la_coef) {
  const int bh = blockIdx.x;
  const int b = bh / NH_, h = bh % NH_;
  const int tid = threadIdx.x;
  __shared__ float buf[CHUNK_ * HS_];

  const float alpha = la_coef[h];
  const float onema = 1.0f - alpha;
  const float* src = xl + (size_t)b * T_ * C_ + h * HS_;
  float* dst = kout + (size_t)bh * T_ * HS_;

  float carry = 0.0f;
  for (int t0 = 0; t0 < T_; t0 += CHUNK_) {
#pragma unroll
    for (int i = 0; i < (CHUNK_ * HS_) / 256; ++i) {
      const int e = tid + i * 256;
      const int tt = e >> 6, d = e & 63;
      buf[e] = src[(size_t)(t0 + tt) * C_ + d];
    }
    __syncthreads();
    if (tid < 64) {
      const int d = tid;
      float c2 = carry;
#pragma unroll 8
      for (int tt = 0; tt < CHUNK_; ++tt) {
        c2 = alpha * c2 + onema * buf[tt * HS_ + d];
        dst[(size_t)(t0 + tt) * HS_ + d] = c2;
      }
      carry = c2;
    }
    __syncthreads();
  }
}

// ---------------------------------------------------------------------------
// Normalize k rows, scale by kb, emit bf16 (B,NH,T,HS).
// ---------------------------------------------------------------------------
__global__ __launch_bounds__(256) void knorm_kernel(const float* __restrict__ kin,
                                                    __hip_bfloat16* __restrict__ kb16,
                                                    const float* __restrict__ kernel_beta) {
  const int row = blockIdx.x * 4 + (threadIdx.x >> 6);
  const int lane = threadIdx.x & 63;
  const int h = (row / T_) % NH_;
  float val = kin[(size_t)row * HS_ + lane];
  float ss = val * val;
#pragma unroll
  for (int m = 32; m; m >>= 1) ss += __shfl_xor(ss, m);
  const float kb = expf(fminf(kernel_beta[h] * 10.0f, 5.0f));
  kb16[(size_t)row * HS_ + lane] = __float2bfloat16(val * (kb / sqrtf(ss)));
}

// ---------------------------------------------------------------------------
// Build v (shift-mix, normalize, scale), emit TRANSPOSED bf16 vT (B,NH,HS,T).
// One block per (bh, 64-t chunk); LDS transpose (stride 66 -> conflict-free).
// ---------------------------------------------------------------------------
__global__ __launch_bounds__(256) void vprep_kernel(const float* __restrict__ xv,
                                                    __hip_bfloat16* __restrict__ vT,
                                                    const float* __restrict__ value_beta,
                                                    const float* __restrict__ v_coef) {
  const int nchunk = T_ / 64;
  const int tc = blockIdx.x % nchunk;
  const int bh = blockIdx.x / nchunk;
  const int h = bh % NH_, b = bh / NH_;
  const int t0 = tc * 64;
  const int w = threadIdx.x >> 6, l = threadIdx.x & 63;
  __shared__ __hip_bfloat16 tile[64][66];

  const float c = v_coef[h];
  const float vb = expf(value_beta[h] * 10.0f);

  for (int r = 0; r < 16; ++r) {
    const int tl = w * 16 + r;
    const int t = t0 + tl;
    const float* base = xv + ((size_t)b * T_ + t) * C_ + h * HS_ + l;
    const float cur = base[0];
    const float nxt = (t + 1 < T_) ? base[C_] : 0.0f;
    float val = nxt * (1.0f - c) + cur * c;
    float ssum = val * val;
#pragma unroll
    for (int m = 32; m; m >>= 1) ssum += __shfl_xor(ssum, m);
    tile[tl][l] = __float2bfloat16(val * (vb / sqrtf(ssum)));
  }
  __syncthreads();
  for (int rr = 0; rr < 16; ++rr) {
    const int hs = w * 16 + rr;
    vT[((size_t)bh * HS_ + hs) * T_ + t0 + l] = tile[l][hs];
  }
}

// ---------------------------------------------------------------------------
// MFMA flash attention (no max-tracking: scores bounded by e^2).
// Block = 4 independent waves, each owns a 16-query strip of a 64-query tile.
// S^T = K Q^T (A=K rows, B=Q rows, both contiguous global bf16 16B loads),
// O^T = V^T P^T (A=vT rows contiguous; B=P^T via packed shfl permutation).
// ---------------------------------------------------------------------------
__global__ __launch_bounds__(256) void attn_mfma_kernel(
    const __hip_bfloat16* __restrict__ kb,   // (BH, T, HS)
    const __hip_bfloat16* __restrict__ vT,   // (BH, HS, T)
    float* __restrict__ y) {                 // (B, T, C)
  const int bh = blockIdx.y;
  const int b = bh / NH_, h = bh % NH_;
  const int qt = (T_ / 64 - 1) - (int)blockIdx.x;  // longest blocks dispatch first
  const int q0 = qt * 64;
  const int w = threadIdx.x >> 6;
  const int l = threadIdx.x & 63;
  const int n = l & 15;
  const int kg = l >> 4;
  const int query = q0 + w * 16 + n;

  const __hip_bfloat16* kbh = kb + (size_t)bh * (T_ * HS_);
  const __hip_bfloat16* vbh = vT + (size_t)bh * (HS_ * T_);

  // Q^T B-fragments: B[k=hs][n=query], lane n holds hs = ks*32 + kg*8 + i
  bf16x8 qf0, qf1;
  {
    const __hip_bfloat16* qrow = kbh + (size_t)query * HS_ + kg * 8;
    qf0 = *reinterpret_cast<const bf16x8*>(qrow);
    qf1 = *reinterpret_cast<const bf16x8*>(qrow + 32);
  }

  f32x4 accO[4];
#pragma unroll
  for (int i = 0; i < 4; ++i) accO[i] = f32x4{0.f, 0.f, 0.f, 0.f};
  float l_acc = 0.0f;

  const int src0 = n + 16 * (2 * (kg & 1));
  const int src1 = src0 + 16;
  const bool hi = (kg >= 2);

  for (int jt = 0; jt <= qt; ++jt) {
    const int j0 = jt * 64;
    const bool diag = (jt == qt);

    // ---- S^T = K @ Q^T : accS[ms][r] = k_{j0+ms*16+kg*4+r} . q_query ----
    f32x4 accS[4];
#pragma unroll
    for (int ms = 0; ms < 4; ++ms) {
      const __hip_bfloat16* krow = kbh + (size_t)(j0 + ms * 16 + n) * HS_ + kg * 8;
      bf16x8 a0 = *reinterpret_cast<const bf16x8*>(krow);
      bf16x8 a1 = *reinterpret_cast<const bf16x8*>(krow + 32);
      f32x4 z{0.f, 0.f, 0.f, 0.f};
      z = __builtin_amdgcn_mfma_f32_16x16x32_bf16(a0, qf0, z, 0, 0, 0);
      accS[ms] = __builtin_amdgcn_mfma_f32_16x16x32_bf16(a1, qf1, z, 0, 0, 0);
    }

    // ---- exp + causal mask (diag tile only) + row-sum l ----
    int pk[4][2];
    float lsum = 0.0f;
    const int qq = w * 16 + n;
#pragma unroll
    for (int ms = 0; ms < 4; ++ms) {
      const int kbase = ms * 16 + kg * 4;
      float p[4];
#pragma unroll
      for (int r = 0; r < 4; ++r) {
        const float e = __expf(accS[ms][r]);
        p[r] = (!diag || (kbase + r < qq)) ? e : 0.0f;
        lsum += p[r];
      }
      pk[ms][0] = pack_bf16(p[0], p[1]);
      pk[ms][1] = pack_bf16(p[2], p[3]);
    }
    lsum += __shfl_xor(lsum, 16);
    lsum += __shfl_xor(lsum, 32);
    l_acc += lsum;

    // ---- O^T += V^T @ P^T ----
#pragma unroll
    for (int ks = 0; ks < 2; ++ks) {
      // build P^T B-frag: lane (n=query, kg) needs keys ks*32+kg*8+[0..7]
      const int wA0a = __shfl(pk[2 * ks][0], src0, 64);
      const int wA0b = __shfl(pk[2 * ks + 1][0], src0, 64);
      const int wA1a = __shfl(pk[2 * ks][1], src0, 64);
      const int wA1b = __shfl(pk[2 * ks + 1][1], src0, 64);
      const int wB0a = __shfl(pk[2 * ks][0], src1, 64);
      const int wB0b = __shfl(pk[2 * ks + 1][0], src1, 64);
      const int wB1a = __shfl(pk[2 * ks][1], src1, 64);
      const int wB1b = __shfl(pk[2 * ks + 1][1], src1, 64);
      union { int i[4]; bf16x8 v; } bp;
      bp.i[0] = hi ? wA0b : wA0a;
      bp.i[1] = hi ? wA1b : wA1a;
      bp.i[2] = hi ? wB0b : wB0a;
      bp.i[3] = hi ? wB1b : wB1a;
#pragma unroll
      for (int mo = 0; mo < 4; ++mo) {
        const __hip_bfloat16* vrow = vbh + (size_t)(mo * 16 + n) * T_ + j0 + ks * 32 + kg * 8;
        bf16x8 av = *reinterpret_cast<const bf16x8*>(vrow);
        accO[mo] = __builtin_amdgcn_mfma_f32_16x16x32_bf16(av, bp.v, accO[mo], 0, 0, 0);
      }
    }
  }

  // ---- epilogue: y[query][h*64+hs] = O^T[hs][query] / l ----
  const float inv = (query == 0) ? 0.0f : 1.0f / l_acc;
  float* yb = y + ((size_t)b * T_ + query) * C_ + h * HS_;
#pragma unroll
  for (int mo = 0; mo < 4; ++mo) {
#pragma unroll
    for (int r = 0; r < 4; ++r) {
      yb[mo * 16 + kg * 4 + r] = accO[mo][r] * inv;
    }
  }
}

// ---------------------------------------------------------------------------
extern "C" void kernel_launch(void* const* d_in, const int* in_sizes, int n_in,
                              void* d_out, int out_size, void* d_ws, size_t ws_size,
                              hipStream_t stream) {
  const float* x           = (const float*)d_in[0];
  const float* W_la        = (const float*)d_in[1];
  const float* la_coef     = (const float*)d_in[2];
  const float* kernel_beta = (const float*)d_in[3];
  const float* value_beta  = (const float*)d_in[4];
  const float* W_v         = (const float*)d_in[5];
  const float* v_coef      = (const float*)d_in[6];
  const float* W_proj      = (const float*)d_in[7];
  float* out = (float*)d_out;

  const size_t NELEM = (size_t)B_ * T_ * C_;  // 4 Mi elements
  char* wsb = (char*)d_ws;
  float* xl    = (float*)(wsb);                      // 16 MB
  float* xv    = (float*)(wsb + 16u * 1024 * 1024);  // 16 MB
  float* kscan = (float*)(wsb + 32u * 1024 * 1024);  // 16 MB
  __hip_bfloat16* kb16 = (__hip_bfloat16*)(wsb + 48u * 1024 * 1024);  // 8 MB
  __hip_bfloat16* vT16 = (__hip_bfloat16*)(wsb + 56u * 1024 * 1024);  // 8 MB
  float* y = xl;  // reuse: xl fully consumed by the scan before attn writes y
  (void)NELEM; (void)ws_size; (void)in_sizes; (void)n_in; (void)out_size;

  const int M = B_ * T_;
  dim3 gg(C_ / 64, M / 64);

  gemm_aw<<<gg, dim3(256), 0, stream>>>(x, W_la, xl, M, C_, C_);
  gemm_aw<<<gg, dim3(256), 0, stream>>>(x, W_v, xv, M, C_, C_);
  ema_scan_kernel<<<dim3(B_ * NH_), dim3(256), 0, stream>>>(xl, kscan, la_coef);
  knorm_kernel<<<dim3(B_ * NH_ * T_ / 4), dim3(256), 0, stream>>>(kscan, kb16, kernel_beta);
  vprep_kernel<<<dim3(B_ * NH_ * (T_ / 64)), dim3(256), 0, stream>>>(xv, vT16, value_beta, v_coef);
  attn_mfma_kernel<<<dim3(T_ / 64, B_ * NH_), dim3(256), 0, stream>>>(kb16, vT16, y);
  gemm_aw<<<gg, dim3(256), 0, stream>>>(y, W_proj, out, M, C_, C_);
}

// Round 4
// 561.625 us; speedup vs baseline: 8.9463x; 1.2950x over previous
//
#include <hip/hip_runtime.h>
#include <hip/hip_bf16.h>

#define B_  2
#define T_  2048
#define NH_ 16
#define HS_ 64
#define C_  1024

typedef __attribute__((ext_vector_type(8))) short bf16x8;
typedef __attribute__((ext_vector_type(4))) float f32x4;

__device__ inline int pack_bf16(float a, float b) {
  union { __hip_bfloat16 h; unsigned short u; } ua, ub;
  ua.h = __float2bfloat16(a);
  ub.h = __float2bfloat16(b);
  return (int)(((unsigned)ub.u << 16) | (unsigned)ua.u);
}

// async global->LDS, 16B per lane. LDS dest must be wave-uniform base + lane*16.
__device__ inline void gl_lds16(const __hip_bfloat16* g, __hip_bfloat16* l) {
  __builtin_amdgcn_global_load_lds(
      (const __attribute__((address_space(1))) unsigned int*)g,
      (__attribute__((address_space(3))) unsigned int*)l, 16, 0, 0);
}

// ---------------------------------------------------------------------------
// fp32 -> bf16 elementwise (n multiple of 2048; 8 elems/thread)
// ---------------------------------------------------------------------------
__global__ __launch_bounds__(256) void cvt_bf16_kernel(const float* __restrict__ in,
                                                       __hip_bfloat16* __restrict__ out) {
  const int i = (blockIdx.x * 256 + threadIdx.x) * 8;
  const float4 a = *reinterpret_cast<const float4*>(in + i);
  const float4 b = *reinterpret_cast<const float4*>(in + i + 4);
  union { int s[4]; int4 v; } u;
  u.s[0] = pack_bf16(a.x, a.y);
  u.s[1] = pack_bf16(a.z, a.w);
  u.s[2] = pack_bf16(b.x, b.y);
  u.s[3] = pack_bf16(b.z, b.w);
  *reinterpret_cast<int4*>(out + i) = u.v;
}

// ---------------------------------------------------------------------------
// W (fp32, K x N = 1024x1024) -> W^T (bf16, N x K). 64x64 LDS tile.
// ---------------------------------------------------------------------------
__global__ __launch_bounds__(256) void cvtT_bf16_kernel(const float* __restrict__ W,
                                                        __hip_bfloat16* __restrict__ WT) {
  __shared__ __hip_bfloat16 tile[64][66];
  const int w = threadIdx.x >> 6, l = threadIdx.x & 63;
  const int n0 = blockIdx.x * 64, k0 = blockIdx.y * 64;
#pragma unroll
  for (int r = 0; r < 16; ++r) {
    const int k = k0 + w * 16 + r;
    tile[w * 16 + r][l] = __float2bfloat16(W[(size_t)k * C_ + n0 + l]);
  }
  __syncthreads();
#pragma unroll
  for (int r = 0; r < 16; ++r) {
    const int nn = w * 16 + r;
    WT[(size_t)(n0 + nn) * C_ + k0 + l] = tile[l][nn];
  }
}

// ---------------------------------------------------------------------------
// MFMA GEMM: C[M,N](fp32) = A(bf16, M x K) @ BT(bf16, N x K)^T.
// 128x128 tile, BK=32, 256 thr (4 waves in 2x2 quadrants), 16 MFMA +
// 8 ds_read_b128 per K-iter, global_load_lds width-16 staging (m97 recipe).
// ---------------------------------------------------------------------------
__global__ __launch_bounds__(256) void gemm_mfma_kernel(const __hip_bfloat16* __restrict__ A,
                                                        const __hip_bfloat16* __restrict__ BT,
                                                        float* __restrict__ Cout,
                                                        int M, int N, int K) {
  __shared__ __hip_bfloat16 As[128 * 32];  // row-major [m][k], no pad (gl_lds order)
  __shared__ __hip_bfloat16 Bs[128 * 32];  // row-major [n][k]
  const int tid = threadIdx.x;
  const int m0 = blockIdx.y * 128, n0 = blockIdx.x * 128;
  const int w = tid >> 6, l = tid & 63;
  const int n = l & 15, kg = l >> 4;
  const int m0w = (w & 1) * 64, n0w = (w >> 1) * 64;

  // staging: chunk c (0..511) = 16B: row c>>2, k-off (c&3)*8; LDS elem off c*8.
  const int r0 = tid >> 2, o0 = (tid & 3) * 8;
  const __hip_bfloat16* ag0 = A + (size_t)(m0 + r0) * K + o0;
  const __hip_bfloat16* ag1 = A + (size_t)(m0 + 64 + r0) * K + o0;
  const __hip_bfloat16* bg0 = BT + (size_t)(n0 + r0) * K + o0;
  const __hip_bfloat16* bg1 = BT + (size_t)(n0 + 64 + r0) * K + o0;
  __hip_bfloat16* al0 = As + tid * 8;
  __hip_bfloat16* al1 = As + (256 + tid) * 8;
  __hip_bfloat16* bl0 = Bs + tid * 8;
  __hip_bfloat16* bl1 = Bs + (256 + tid) * 8;

  f32x4 acc[4][4];
#pragma unroll
  for (int i = 0; i < 4; ++i)
#pragma unroll
    for (int j = 0; j < 4; ++j) acc[i][j] = f32x4{0.f, 0.f, 0.f, 0.f};

  for (int k0 = 0; k0 < K; k0 += 32) {
    gl_lds16(ag0 + k0, al0);
    gl_lds16(ag1 + k0, al1);
    gl_lds16(bg0 + k0, bl0);
    gl_lds16(bg1 + k0, bl1);
    __syncthreads();
    bf16x8 af[4], bf[4];
#pragma unroll
    for (int ms = 0; ms < 4; ++ms)
      af[ms] = *reinterpret_cast<const bf16x8*>(As + (m0w + ms * 16 + n) * 32 + kg * 8);
#pragma unroll
    for (int ns = 0; ns < 4; ++ns)
      bf[ns] = *reinterpret_cast<const bf16x8*>(Bs + (n0w + ns * 16 + n) * 32 + kg * 8);
#pragma unroll
    for (int ms = 0; ms < 4; ++ms)
#pragma unroll
      for (int ns = 0; ns < 4; ++ns)
        acc[ms][ns] = __builtin_amdgcn_mfma_f32_16x16x32_bf16(af[ms], bf[ns], acc[ms][ns], 0, 0, 0);
    __syncthreads();
  }

#pragma unroll
  for (int ms = 0; ms < 4; ++ms) {
#pragma unroll
    for (int r = 0; r < 4; ++r) {
      const int row = m0 + m0w + ms * 16 + kg * 4 + r;
      float* cp = Cout + (size_t)row * N + n0 + n0w + n;
#pragma unroll
      for (int ns = 0; ns < 4; ++ns) cp[ns * 16] = acc[ms][ns][r];
    }
  }
}

// ---------------------------------------------------------------------------
// Fused EMA scan + row-norm + kb scale. One block per (b,h). Per 256-t chunk:
// stage -> wave0 sequential scan (writes LDS in place) -> 4 waves normalize
// 64 rows each -> bf16 k out (B,NH,T,HS).
// ---------------------------------------------------------------------------
#define CHUNK_ 256
__global__ __launch_bounds__(256) void ema_scan_norm_kernel(const float* __restrict__ xl,
                                                            __hip_bfloat16* __restrict__ kb16,
                                                            const float* __restrict__ la_coef,
                                                            const float* __restrict__ kernel_beta) {
  const int bh = blockIdx.x;
  const int b = bh / NH_, h = bh % NH_;
  const int tid = threadIdx.x;
  const int w = tid >> 6, l = tid & 63;
  __shared__ float buf[CHUNK_ * HS_];

  const float alpha = la_coef[h];
  const float onema = 1.0f - alpha;
  const float kbs = expf(fminf(kernel_beta[h] * 10.0f, 5.0f));
  const float* src = xl + (size_t)b * T_ * C_ + h * HS_;
  __hip_bfloat16* dst = kb16 + (size_t)bh * T_ * HS_;

  float carry = 0.0f;
  for (int t0 = 0; t0 < T_; t0 += CHUNK_) {
#pragma unroll
    for (int i = 0; i < (CHUNK_ * HS_) / 256; ++i) {
      const int e = tid + i * 256;
      const int tt = e >> 6, d = e & 63;
      buf[e] = src[(size_t)(t0 + tt) * C_ + d];
    }
    __syncthreads();
    if (tid < 64) {
      const int d = tid;
      float c2 = carry;
#pragma unroll 8
      for (int tt = 0; tt < CHUNK_; ++tt) {
        c2 = alpha * c2 + onema * buf[tt * HS_ + d];
        buf[tt * HS_ + d] = c2;
      }
      carry = c2;
    }
    __syncthreads();
    // norm phase: wave w handles rows w*64 .. w*64+63 of this chunk
    for (int rr = 0; rr < 64; ++rr) {
      const int tl = w * 64 + rr;
      const float val = buf[tl * HS_ + l];
      float ss = val * val;
#pragma unroll
      for (int m = 32; m; m >>= 1) ss += __shfl_xor(ss, m);
      dst[(size_t)(t0 + tl) * HS_ + l] = __float2bfloat16(val * (kbs / sqrtf(ss)));
    }
    __syncthreads();
  }
}

// ---------------------------------------------------------------------------
// Build v (shift-mix, normalize, scale), emit TRANSPOSED bf16 vT (B,NH,HS,T).
// ---------------------------------------------------------------------------
__global__ __launch_bounds__(256) void vprep_kernel(const float* __restrict__ xv,
                                                    __hip_bfloat16* __restrict__ vT,
                                                    const float* __restrict__ value_beta,
                                                    const float* __restrict__ v_coef) {
  const int nchunk = T_ / 64;
  const int tc = blockIdx.x % nchunk;
  const int bh = blockIdx.x / nchunk;
  const int h = bh % NH_, b = bh / NH_;
  const int t0 = tc * 64;
  const int w = threadIdx.x >> 6, l = threadIdx.x & 63;
  __shared__ __hip_bfloat16 tile[64][66];

  const float c = v_coef[h];
  const float vb = expf(value_beta[h] * 10.0f);

  for (int r = 0; r < 16; ++r) {
    const int tl = w * 16 + r;
    const int t = t0 + tl;
    const float* base = xv + ((size_t)b * T_ + t) * C_ + h * HS_ + l;
    const float cur = base[0];
    const float nxt = (t + 1 < T_) ? base[C_] : 0.0f;
    float val = nxt * (1.0f - c) + cur * c;
    float ssum = val * val;
#pragma unroll
    for (int m = 32; m; m >>= 1) ssum += __shfl_xor(ssum, m);
    tile[tl][l] = __float2bfloat16(val * (vb / sqrtf(ssum)));
  }
  __syncthreads();
  for (int rr = 0; rr < 16; ++rr) {
    const int hs = w * 16 + rr;
    vT[((size_t)bh * HS_ + hs) * T_ + t0 + l] = tile[l][hs];
  }
}

// ---------------------------------------------------------------------------
// MFMA flash attention (no max-tracking: scores bounded by e^2).
// Output y emitted directly as bf16 (B,T,C) for the MFMA projection GEMM.
// ---------------------------------------------------------------------------
__global__ __launch_bounds__(256) void attn_mfma_kernel(
    const __hip_bfloat16* __restrict__ kb,   // (BH, T, HS)
    const __hip_bfloat16* __restrict__ vT,   // (BH, HS, T)
    __hip_bfloat16* __restrict__ y) {        // (B, T, C) bf16
  const int bh = blockIdx.y;
  const int b = bh / NH_, h = bh % NH_;
  const int qt = (T_ / 64 - 1) - (int)blockIdx.x;  // longest blocks dispatch first
  const int q0 = qt * 64;
  const int w = threadIdx.x >> 6;
  const int l = threadIdx.x & 63;
  const int n = l & 15;
  const int kg = l >> 4;
  const int query = q0 + w * 16 + n;

  const __hip_bfloat16* kbh = kb + (size_t)bh * (T_ * HS_);
  const __hip_bfloat16* vbh = vT + (size_t)bh * (HS_ * T_);

  bf16x8 qf0, qf1;
  {
    const __hip_bfloat16* qrow = kbh + (size_t)query * HS_ + kg * 8;
    qf0 = *reinterpret_cast<const bf16x8*>(qrow);
    qf1 = *reinterpret_cast<const bf16x8*>(qrow + 32);
  }

  f32x4 accO[4];
#pragma unroll
  for (int i = 0; i < 4; ++i) accO[i] = f32x4{0.f, 0.f, 0.f, 0.f};
  float l_acc = 0.0f;

  const int src0 = n + 16 * (2 * (kg & 1));
  const int src1 = src0 + 16;
  const bool hi = (kg >= 2);

  for (int jt = 0; jt <= qt; ++jt) {
    const int j0 = jt * 64;
    const bool diag = (jt == qt);

    f32x4 accS[4];
#pragma unroll
    for (int ms = 0; ms < 4; ++ms) {
      const __hip_bfloat16* krow = kbh + (size_t)(j0 + ms * 16 + n) * HS_ + kg * 8;
      bf16x8 a0 = *reinterpret_cast<const bf16x8*>(krow);
      bf16x8 a1 = *reinterpret_cast<const bf16x8*>(krow + 32);
      f32x4 z{0.f, 0.f, 0.f, 0.f};
      z = __builtin_amdgcn_mfma_f32_16x16x32_bf16(a0, qf0, z, 0, 0, 0);
      accS[ms] = __builtin_amdgcn_mfma_f32_16x16x32_bf16(a1, qf1, z, 0, 0, 0);
    }

    int pk[4][2];
    float lsum = 0.0f;
    const int qq = w * 16 + n;
#pragma unroll
    for (int ms = 0; ms < 4; ++ms) {
      const int kbase = ms * 16 + kg * 4;
      float p[4];
#pragma unroll
      for (int r = 0; r < 4; ++r) {
        const float e = __expf(accS[ms][r]);
        p[r] = (!diag || (kbase + r < qq)) ? e : 0.0f;
        lsum += p[r];
      }
      pk[ms][0] = pack_bf16(p[0], p[1]);
      pk[ms][1] = pack_bf16(p[2], p[3]);
    }
    lsum += __shfl_xor(lsum, 16);
    lsum += __shfl_xor(lsum, 32);
    l_acc += lsum;

#pragma unroll
    for (int ks = 0; ks < 2; ++ks) {
      const int wA0a = __shfl(pk[2 * ks][0], src0, 64);
      const int wA0b = __shfl(pk[2 * ks + 1][0], src0, 64);
      const int wA1a = __shfl(pk[2 * ks][1], src0, 64);
      const int wA1b = __shfl(pk[2 * ks + 1][1], src0, 64);
      const int wB0a = __shfl(pk[2 * ks][0], src1, 64);
      const int wB0b = __shfl(pk[2 * ks + 1][0], src1, 64);
      const int wB1a = __shfl(pk[2 * ks][1], src1, 64);
      const int wB1b = __shfl(pk[2 * ks + 1][1], src1, 64);
      union { int i[4]; bf16x8 v; } bp;
      bp.i[0] = hi ? wA0b : wA0a;
      bp.i[1] = hi ? wA1b : wA1a;
      bp.i[2] = hi ? wB0b : wB0a;
      bp.i[3] = hi ? wB1b : wB1a;
#pragma unroll
      for (int mo = 0; mo < 4; ++mo) {
        const __hip_bfloat16* vrow = vbh + (size_t)(mo * 16 + n) * T_ + j0 + ks * 32 + kg * 8;
        bf16x8 av = *reinterpret_cast<const bf16x8*>(vrow);
        accO[mo] = __builtin_amdgcn_mfma_f32_16x16x32_bf16(av, bp.v, accO[mo], 0, 0, 0);
      }
    }
  }

  const float inv = (query == 0) ? 0.0f : 1.0f / l_acc;
  __hip_bfloat16* yb = y + ((size_t)b * T_ + query) * C_ + h * HS_;
#pragma unroll
  for (int mo = 0; mo < 4; ++mo) {
    int2 pkd;
    pkd.x = pack_bf16(accO[mo][0] * inv, accO[mo][1] * inv);
    pkd.y = pack_bf16(accO[mo][2] * inv, accO[mo][3] * inv);
    *reinterpret_cast<int2*>(yb + mo * 16 + kg * 4) = pkd;
  }
}

// ---------------------------------------------------------------------------
extern "C" void kernel_launch(void* const* d_in, const int* in_sizes, int n_in,
                              void* d_out, int out_size, void* d_ws, size_t ws_size,
                              hipStream_t stream) {
  const float* x           = (const float*)d_in[0];
  const float* W_la        = (const float*)d_in[1];
  const float* la_coef     = (const float*)d_in[2];
  const float* kernel_beta = (const float*)d_in[3];
  const float* value_beta  = (const float*)d_in[4];
  const float* W_v         = (const float*)d_in[5];
  const float* v_coef      = (const float*)d_in[6];
  const float* W_proj      = (const float*)d_in[7];
  float* out = (float*)d_out;

  char* wsb = (char*)d_ws;
  const size_t MB = 1024u * 1024u;
  __hip_bfloat16* x16    = (__hip_bfloat16*)(wsb);            // 8 MB
  __hip_bfloat16* WlaT   = (__hip_bfloat16*)(wsb + 8 * MB);   // 2 MB
  __hip_bfloat16* WvT    = (__hip_bfloat16*)(wsb + 10 * MB);  // 2 MB
  __hip_bfloat16* WprojT = (__hip_bfloat16*)(wsb + 12 * MB);  // 2 MB
  float* xl              = (float*)(wsb + 16 * MB);           // 16 MB
  float* xv              = (float*)(wsb + 32 * MB);           // 16 MB
  __hip_bfloat16* kb16   = (__hip_bfloat16*)(wsb + 48 * MB);  // 8 MB
  __hip_bfloat16* vT16   = (__hip_bfloat16*)(wsb + 56 * MB);  // 8 MB
  __hip_bfloat16* y16    = (__hip_bfloat16*)(wsb + 16 * MB);  // aliases xl (consumed by scan)
  (void)ws_size; (void)in_sizes; (void)n_in; (void)out_size;

  const int M = B_ * T_;
  dim3 ggm(C_ / 128, M / 128);  // (8, 32)
  dim3 ggt(C_ / 64, C_ / 64);   // (16, 16)

  cvt_bf16_kernel<<<dim3((M * C_) / 2048), dim3(256), 0, stream>>>(x, x16);
  cvtT_bf16_kernel<<<ggt, dim3(256), 0, stream>>>(W_la, WlaT);
  cvtT_bf16_kernel<<<ggt, dim3(256), 0, stream>>>(W_v, WvT);
  cvtT_bf16_kernel<<<ggt, dim3(256), 0, stream>>>(W_proj, WprojT);

  gemm_mfma_kernel<<<ggm, dim3(256), 0, stream>>>(x16, WlaT, xl, M, C_, C_);
  gemm_mfma_kernel<<<ggm, dim3(256), 0, stream>>>(x16, WvT, xv, M, C_, C_);
  ema_scan_norm_kernel<<<dim3(B_ * NH_), dim3(256), 0, stream>>>(xl, kb16, la_coef, kernel_beta);
  vprep_kernel<<<dim3(B_ * NH_ * (T_ / 64)), dim3(256), 0, stream>>>(xv, vT16, value_beta, v_coef);
  attn_mfma_kernel<<<dim3(T_ / 64, B_ * NH_), dim3(256), 0, stream>>>(kb16, vT16, y16);
  gemm_mfma_kernel<<<ggm, dim3(256), 0, stream>>>(y16, WprojT, out, M, C_, C_);
}

// Round 6
// 416.249 us; speedup vs baseline: 12.0708x; 1.3493x over previous
//
#include <hip/hip_runtime.h>
#include <hip/hip_bf16.h>

#define B_  2
#define T_  2048
#define NH_ 16
#define HS_ 64
#define C_  1024

typedef __attribute__((ext_vector_type(8))) short bf16x8;
typedef __attribute__((ext_vector_type(4))) float f32x4;

__device__ inline int pack_bf16(float a, float b) {
  union { __hip_bfloat16 h; unsigned short u; } ua, ub;
  ua.h = __float2bfloat16(a);
  ub.h = __float2bfloat16(b);
  return (int)(((unsigned)ub.u << 16) | (unsigned)ua.u);
}

// async global->LDS 16B: NOTE global ptr is PER-LANE; LDS dest is
// wave-uniform base + lane*16. Callers must pass per-lane g AND l = base+lane*16.
__device__ inline void gl_lds16(const __hip_bfloat16* g, __hip_bfloat16* l) {
  __builtin_amdgcn_global_load_lds(
      (const __attribute__((address_space(1))) unsigned int*)g,
      (__attribute__((address_space(3))) unsigned int*)l, 16, 0, 0);
}

// ---------------------------------------------------------------------------
// fp32 -> bf16 elementwise (n multiple of 2048; 8 elems/thread)
// ---------------------------------------------------------------------------
__global__ __launch_bounds__(256) void cvt_bf16_kernel(const float* __restrict__ in,
                                                       __hip_bfloat16* __restrict__ out) {
  const int i = (blockIdx.x * 256 + threadIdx.x) * 8;
  const float4 a = *reinterpret_cast<const float4*>(in + i);
  const float4 b = *reinterpret_cast<const float4*>(in + i + 4);
  union { int s[4]; int4 v; } u;
  u.s[0] = pack_bf16(a.x, a.y);
  u.s[1] = pack_bf16(a.z, a.w);
  u.s[2] = pack_bf16(b.x, b.y);
  u.s[3] = pack_bf16(b.z, b.w);
  *reinterpret_cast<int4*>(out + i) = u.v;
}

// ---------------------------------------------------------------------------
// W (fp32, K x N = 1024x1024) -> W^T (bf16, N x K). 64x64 LDS tile.
// ---------------------------------------------------------------------------
__global__ __launch_bounds__(256) void cvtT_bf16_kernel(const float* __restrict__ W,
                                                        __hip_bfloat16* __restrict__ WT) {
  __shared__ __hip_bfloat16 tile[64][66];
  const int w = threadIdx.x >> 6, l = threadIdx.x & 63;
  const int n0 = blockIdx.x * 64, k0 = blockIdx.y * 64;
#pragma unroll
  for (int r = 0; r < 16; ++r) {
    const int k = k0 + w * 16 + r;
    tile[w * 16 + r][l] = __float2bfloat16(W[(size_t)k * C_ + n0 + l]);
  }
  __syncthreads();
#pragma unroll
  for (int r = 0; r < 16; ++r) {
    const int nn = w * 16 + r;
    WT[(size_t)(n0 + nn) * C_ + k0 + l] = tile[l][nn];
  }
}

// ---------------------------------------------------------------------------
// MFMA GEMM: C[M,N](fp32) = A(bf16, M x K) @ BT(bf16, N x K)^T. m97 recipe.
// ---------------------------------------------------------------------------
__global__ __launch_bounds__(256) void gemm_mfma_kernel(const __hip_bfloat16* __restrict__ A,
                                                        const __hip_bfloat16* __restrict__ BT,
                                                        float* __restrict__ Cout,
                                                        int M, int N, int K) {
  __shared__ __hip_bfloat16 As[128 * 32];
  __shared__ __hip_bfloat16 Bs[128 * 32];
  const int tid = threadIdx.x;
  const int m0 = blockIdx.y * 128, n0 = blockIdx.x * 128;
  const int w = tid >> 6, l = tid & 63;
  const int n = l & 15, kg = l >> 4;
  const int m0w = (w & 1) * 64, n0w = (w >> 1) * 64;

  const int r0 = tid >> 2, o0 = (tid & 3) * 8;
  const __hip_bfloat16* ag0 = A + (size_t)(m0 + r0) * K + o0;
  const __hip_bfloat16* ag1 = A + (size_t)(m0 + 64 + r0) * K + o0;
  const __hip_bfloat16* bg0 = BT + (size_t)(n0 + r0) * K + o0;
  const __hip_bfloat16* bg1 = BT + (size_t)(n0 + 64 + r0) * K + o0;
  __hip_bfloat16* al0 = As + tid * 8;
  __hip_bfloat16* al1 = As + (256 + tid) * 8;
  __hip_bfloat16* bl0 = Bs + tid * 8;
  __hip_bfloat16* bl1 = Bs + (256 + tid) * 8;

  f32x4 acc[4][4];
#pragma unroll
  for (int i = 0; i < 4; ++i)
#pragma unroll
    for (int j = 0; j < 4; ++j) acc[i][j] = f32x4{0.f, 0.f, 0.f, 0.f};

  for (int k0 = 0; k0 < K; k0 += 32) {
    gl_lds16(ag0 + k0, al0);
    gl_lds16(ag1 + k0, al1);
    gl_lds16(bg0 + k0, bl0);
    gl_lds16(bg1 + k0, bl1);
    __syncthreads();
    bf16x8 af[4], bf[4];
#pragma unroll
    for (int ms = 0; ms < 4; ++ms)
      af[ms] = *reinterpret_cast<const bf16x8*>(As + (m0w + ms * 16 + n) * 32 + kg * 8);
#pragma unroll
    for (int ns = 0; ns < 4; ++ns)
      bf[ns] = *reinterpret_cast<const bf16x8*>(Bs + (n0w + ns * 16 + n) * 32 + kg * 8);
#pragma unroll
    for (int ms = 0; ms < 4; ++ms)
#pragma unroll
      for (int ns = 0; ns < 4; ++ns)
        acc[ms][ns] = __builtin_amdgcn_mfma_f32_16x16x32_bf16(af[ms], bf[ns], acc[ms][ns], 0, 0, 0);
    __syncthreads();
  }

#pragma unroll
  for (int ms = 0; ms < 4; ++ms) {
#pragma unroll
    for (int r = 0; r < 4; ++r) {
      const int row = m0 + m0w + ms * 16 + kg * 4 + r;
      float* cp = Cout + (size_t)row * N + n0 + n0w + n;
#pragma unroll
      for (int ns = 0; ns < 4; ++ns) cp[ns * 16] = acc[ms][ns][r];
    }
  }
}

// ---------------------------------------------------------------------------
// Fused EMA scan + row-norm + kb scale -> bf16 k (B,NH,T,HS).
// ---------------------------------------------------------------------------
#define CHUNK_ 256
__global__ __launch_bounds__(256) void ema_scan_norm_kernel(const float* __restrict__ xl,
                                                            __hip_bfloat16* __restrict__ kb16,
                                                            const float* __restrict__ la_coef,
                                                            const float* __restrict__ kernel_beta) {
  const int bh = blockIdx.x;
  const int b = bh / NH_, h = bh % NH_;
  const int tid = threadIdx.x;
  const int w = tid >> 6, l = tid & 63;
  __shared__ float buf[CHUNK_ * HS_];

  const float alpha = la_coef[h];
  const float onema = 1.0f - alpha;
  const float kbs = expf(fminf(kernel_beta[h] * 10.0f, 5.0f));
  const float* src = xl + (size_t)b * T_ * C_ + h * HS_;
  __hip_bfloat16* dst = kb16 + (size_t)bh * T_ * HS_;

  float carry = 0.0f;
  for (int t0 = 0; t0 < T_; t0 += CHUNK_) {
#pragma unroll
    for (int i = 0; i < (CHUNK_ * HS_) / 256; ++i) {
      const int e = tid + i * 256;
      const int tt = e >> 6, d = e & 63;
      buf[e] = src[(size_t)(t0 + tt) * C_ + d];
    }
    __syncthreads();
    if (tid < 64) {
      const int d = tid;
      float c2 = carry;
#pragma unroll 8
      for (int tt = 0; tt < CHUNK_; ++tt) {
        c2 = alpha * c2 + onema * buf[tt * HS_ + d];
        buf[tt * HS_ + d] = c2;
      }
      carry = c2;
    }
    __syncthreads();
    for (int rr = 0; rr < 64; ++rr) {
      const int tl = w * 64 + rr;
      const float val = buf[tl * HS_ + l];
      float ss = val * val;
#pragma unroll
      for (int m = 32; m; m >>= 1) ss += __shfl_xor(ss, m);
      dst[(size_t)(t0 + tl) * HS_ + l] = __float2bfloat16(val * (kbs / sqrtf(ss)));
    }
    __syncthreads();
  }
}

// ---------------------------------------------------------------------------
// Build v (shift-mix, normalize, scale), emit TILE-MAJOR transposed bf16
// vt (BH, T/64, HS, 64): each 64-key tile is 8KB contiguous for DMA staging.
// ---------------------------------------------------------------------------
__global__ __launch_bounds__(256) void vprep_kernel(const float* __restrict__ xv,
                                                    __hip_bfloat16* __restrict__ vt,
                                                    const float* __restrict__ value_beta,
                                                    const float* __restrict__ v_coef) {
  const int nchunk = T_ / 64;
  const int tc = blockIdx.x % nchunk;
  const int bh = blockIdx.x / nchunk;
  const int h = bh % NH_, b = bh / NH_;
  const int t0 = tc * 64;
  const int w = threadIdx.x >> 6, l = threadIdx.x & 63;
  __shared__ __hip_bfloat16 tile[64][66];

  const float c = v_coef[h];
  const float vb = expf(value_beta[h] * 10.0f);

  for (int r = 0; r < 16; ++r) {
    const int tl = w * 16 + r;
    const int t = t0 + tl;
    const float* base = xv + ((size_t)b * T_ + t) * C_ + h * HS_ + l;
    const float cur = base[0];
    const float nxt = (t + 1 < T_) ? base[C_] : 0.0f;
    float val = nxt * (1.0f - c) + cur * c;
    float ssum = val * val;
#pragma unroll
    for (int m = 32; m; m >>= 1) ssum += __shfl_xor(ssum, m);
    tile[tl][l] = __float2bfloat16(val * (vb / sqrtf(ssum)));
  }
  __syncthreads();
  __hip_bfloat16* vtb = vt + (((size_t)bh * nchunk + tc) * HS_) * 64;
  for (int rr = 0; rr < 16; ++rr) {
    const int hs = w * 16 + rr;
    vtb[(size_t)hs * 64 + l] = tile[l][hs];
  }
}

// ---------------------------------------------------------------------------
// MFMA flash attention, LDS-staged (m97 pattern).
// Block = 64 queries (4 waves x 16-q strips). Per 64-key j-tile:
//   DMA K-tile + V-tile (8KB each, contiguous) into LDS via global_load_lds
//   (PER-LANE global addr + base+lane*16 LDS addr),
//   S^T = K @ Q^T, exp/mask/row-sum, P via per-wave LDS round-trip,
//   O^T += V^T @ P^T.  Scores bounded by e^2 -> no online max needed.
// ---------------------------------------------------------------------------
__global__ __launch_bounds__(256) void attn_mfma_kernel(
    const __hip_bfloat16* __restrict__ kb,   // (BH, T, HS)
    const __hip_bfloat16* __restrict__ vt,   // (BH, T/64, HS, 64) tile-major
    __hip_bfloat16* __restrict__ y) {        // (B, T, C) bf16
  __shared__ __hip_bfloat16 Ks[64 * 64];     // [key][hs]
  __shared__ __hip_bfloat16 Vs[64 * 64];     // [hs][key]
  __shared__ __hip_bfloat16 Ps[4][16 * 68];  // per-wave P: [query][key], pad 68

  const int bh = blockIdx.y;
  const int b = bh / NH_, h = bh % NH_;
  const int qt = (T_ / 64 - 1) - (int)blockIdx.x;  // longest first
  const int q0 = qt * 64;
  const int w = threadIdx.x >> 6;
  const int l = threadIdx.x & 63;
  const int n = l & 15;
  const int kg = l >> 4;
  const int query = q0 + w * 16 + n;
  const int lo = l * 8;  // per-lane 16B offset (elements)

  const __hip_bfloat16* kbh = kb + (size_t)bh * (T_ * HS_);
  const __hip_bfloat16* vbh = vt + (size_t)bh * (T_ * HS_);

  // Q B-fragments from global (once): lane n holds q_query[hs=kg*8+j (+32)]
  bf16x8 qf0, qf1;
  {
    const __hip_bfloat16* qrow = kbh + (size_t)query * HS_ + kg * 8;
    qf0 = *reinterpret_cast<const bf16x8*>(qrow);
    qf1 = *reinterpret_cast<const bf16x8*>(qrow + 32);
  }

  f32x4 accO[4];
#pragma unroll
  for (int i = 0; i < 4; ++i) accO[i] = f32x4{0.f, 0.f, 0.f, 0.f};
  float l_acc = 0.0f;

  __hip_bfloat16* Pw = Ps[w];
  int* Pwi = reinterpret_cast<int*>(Pw);

  for (int jt = 0; jt <= qt; ++jt) {
    const int j0 = jt * 64;
    const bool diag = (jt == qt);

    // ---- stage K tile + V tile: each wave covers 16 rows (2 x 8-row DMAs) ----
    {
      const __hip_bfloat16* kgp = kbh + (size_t)(j0 + w * 16) * HS_ + lo;
      __hip_bfloat16* kls = Ks + w * 16 * 64 + lo;
      gl_lds16(kgp, kls);
      gl_lds16(kgp + 512, kls + 512);
      const __hip_bfloat16* vgp = vbh + (size_t)jt * (64 * HS_) + (size_t)(w * 16) * 64 + lo;
      __hip_bfloat16* vls = Vs + w * 16 * 64 + lo;
      gl_lds16(vgp, vls);
      gl_lds16(vgp + 512, vls + 512);
    }
    __syncthreads();

    // ---- S^T = K @ Q^T ----
    f32x4 accS[4];
#pragma unroll
    for (int ms = 0; ms < 4; ++ms) {
      const __hip_bfloat16* kr = Ks + (ms * 16 + n) * 64 + kg * 8;
      bf16x8 a0 = *reinterpret_cast<const bf16x8*>(kr);
      bf16x8 a1 = *reinterpret_cast<const bf16x8*>(kr + 32);
      f32x4 z{0.f, 0.f, 0.f, 0.f};
      z = __builtin_amdgcn_mfma_f32_16x16x32_bf16(a0, qf0, z, 0, 0, 0);
      accS[ms] = __builtin_amdgcn_mfma_f32_16x16x32_bf16(a1, qf1, z, 0, 0, 0);
    }

    // ---- exp + causal mask + row-sum; write P[query][key] to wave-local LDS ----
    float lsum = 0.0f;
    const int qq = w * 16 + n;
#pragma unroll
    for (int ms = 0; ms < 4; ++ms) {
      const int kbase = ms * 16 + kg * 4;
      float p[4];
#pragma unroll
      for (int r = 0; r < 4; ++r) {
        const float e = __expf(accS[ms][r]);
        p[r] = (!diag || (kbase + r < qq)) ? e : 0.0f;
        lsum += p[r];
      }
      const int po = n * 34 + ms * 8 + kg * 2;  // int offset: (n*68+ms*16+kg*4)/2
      Pwi[po] = pack_bf16(p[0], p[1]);
      Pwi[po + 1] = pack_bf16(p[2], p[3]);
    }
    lsum += __shfl_xor(lsum, 16);
    lsum += __shfl_xor(lsum, 32);
    l_acc += lsum;

    // ---- O^T += V^T @ P^T (P B-frag read back from wave-local LDS) ----
#pragma unroll
    for (int ks = 0; ks < 2; ++ks) {
      union { ushort4 u[2]; bf16x8 v; } pr;
      const __hip_bfloat16* pp = Pw + n * 68 + ks * 32 + kg * 8;
      pr.u[0] = *reinterpret_cast<const ushort4*>(pp);
      pr.u[1] = *reinterpret_cast<const ushort4*>(pp + 4);
#pragma unroll
      for (int mo = 0; mo < 4; ++mo) {
        const __hip_bfloat16* vr = Vs + (mo * 16 + n) * 64 + ks * 32 + kg * 8;
        bf16x8 av = *reinterpret_cast<const bf16x8*>(vr);
        accO[mo] = __builtin_amdgcn_mfma_f32_16x16x32_bf16(av, pr.v, accO[mo], 0, 0, 0);
      }
    }
    __syncthreads();
  }

  // ---- epilogue: y[query][h*64+hs] = O^T[hs][query] / l ----
  const float inv = (query == 0) ? 0.0f : 1.0f / l_acc;
  __hip_bfloat16* yb = y + ((size_t)b * T_ + query) * C_ + h * HS_;
#pragma unroll
  for (int mo = 0; mo < 4; ++mo) {
    int2 pkd;
    pkd.x = pack_bf16(accO[mo][0] * inv, accO[mo][1] * inv);
    pkd.y = pack_bf16(accO[mo][2] * inv, accO[mo][3] * inv);
    *reinterpret_cast<int2*>(yb + mo * 16 + kg * 4) = pkd;
  }
}

// ---------------------------------------------------------------------------
extern "C" void kernel_launch(void* const* d_in, const int* in_sizes, int n_in,
                              void* d_out, int out_size, void* d_ws, size_t ws_size,
                              hipStream_t stream) {
  const float* x           = (const float*)d_in[0];
  const float* W_la        = (const float*)d_in[1];
  const float* la_coef     = (const float*)d_in[2];
  const float* kernel_beta = (const float*)d_in[3];
  const float* value_beta  = (const float*)d_in[4];
  const float* W_v         = (const float*)d_in[5];
  const float* v_coef      = (const float*)d_in[6];
  const float* W_proj      = (const float*)d_in[7];
  float* out = (float*)d_out;

  char* wsb = (char*)d_ws;
  const size_t MB = 1024u * 1024u;
  __hip_bfloat16* x16    = (__hip_bfloat16*)(wsb);            // 8 MB
  __hip_bfloat16* WlaT   = (__hip_bfloat16*)(wsb + 8 * MB);   // 2 MB
  __hip_bfloat16* WvT    = (__hip_bfloat16*)(wsb + 10 * MB);  // 2 MB
  __hip_bfloat16* WprojT = (__hip_bfloat16*)(wsb + 12 * MB);  // 2 MB
  float* xl              = (float*)(wsb + 16 * MB);           // 16 MB
  float* xv              = (float*)(wsb + 32 * MB);           // 16 MB
  __hip_bfloat16* kb16   = (__hip_bfloat16*)(wsb + 48 * MB);  // 8 MB
  __hip_bfloat16* vt16   = (__hip_bfloat16*)(wsb + 56 * MB);  // 8 MB
  __hip_bfloat16* y16    = (__hip_bfloat16*)(wsb + 16 * MB);  // aliases xl (consumed by scan)
  (void)ws_size; (void)in_sizes; (void)n_in; (void)out_size;

  const int M = B_ * T_;
  dim3 ggm(C_ / 128, M / 128);  // (8, 32)
  dim3 ggt(C_ / 64, C_ / 64);   // (16, 16)

  cvt_bf16_kernel<<<dim3((M * C_) / 2048), dim3(256), 0, stream>>>(x, x16);
  cvtT_bf16_kernel<<<ggt, dim3(256), 0, stream>>>(W_la, WlaT);
  cvtT_bf16_kernel<<<ggt, dim3(256), 0, stream>>>(W_v, WvT);
  cvtT_bf16_kernel<<<ggt, dim3(256), 0, stream>>>(W_proj, WprojT);

  gemm_mfma_kernel<<<ggm, dim3(256), 0, stream>>>(x16, WlaT, xl, M, C_, C_);
  gemm_mfma_kernel<<<ggm, dim3(256), 0, stream>>>(x16, WvT, xv, M, C_, C_);
  ema_scan_norm_kernel<<<dim3(B_ * NH_), dim3(256), 0, stream>>>(xl, kb16, la_coef, kernel_beta);
  vprep_kernel<<<dim3(B_ * NH_ * (T_ / 64)), dim3(256), 0, stream>>>(xv, vt16, value_beta, v_coef);
  attn_mfma_kernel<<<dim3(T_ / 64, B_ * NH_), dim3(256), 0, stream>>>(kb16, vt16, y16);
  gemm_mfma_kernel<<<ggm, dim3(256), 0, stream>>>(y16, WprojT, out, M, C_, C_);
}

// Round 7
// 298.901 us; speedup vs baseline: 16.8097x; 1.3926x over previous
//
#include <hip/hip_runtime.h>
#include <hip/hip_bf16.h>

#define B_  2
#define T_  2048
#define NH_ 16
#define HS_ 64
#define C_  1024
#define SCL_ 128              // EMA chunk length
#define SCN_ (T_ / SCL_)      // 16 chunks

typedef __attribute__((ext_vector_type(8))) short bf16x8;
typedef __attribute__((ext_vector_type(4))) float f32x4;

__device__ inline int pack_bf16(float a, float b) {
  union { __hip_bfloat16 h; unsigned short u; } ua, ub;
  ua.h = __float2bfloat16(a);
  ub.h = __float2bfloat16(b);
  return (int)(((unsigned)ub.u << 16) | (unsigned)ua.u);
}

// async global->LDS 16B: global ptr is PER-LANE; LDS dest must equal
// wave-uniform base + lane*16. Callers pass per-lane g AND l = base+lane*16.
__device__ inline void gl_lds16(const __hip_bfloat16* g, __hip_bfloat16* l) {
  __builtin_amdgcn_global_load_lds(
      (const __attribute__((address_space(1))) unsigned int*)g,
      (__attribute__((address_space(3))) unsigned int*)l, 16, 0, 0);
}

// ---------------------------------------------------------------------------
// fp32 -> bf16 elementwise (n multiple of 2048; 8 elems/thread)
// ---------------------------------------------------------------------------
__global__ __launch_bounds__(256) void cvt_bf16_kernel(const float* __restrict__ in,
                                                       __hip_bfloat16* __restrict__ out) {
  const int i = (blockIdx.x * 256 + threadIdx.x) * 8;
  const float4 a = *reinterpret_cast<const float4*>(in + i);
  const float4 b = *reinterpret_cast<const float4*>(in + i + 4);
  union { int s[4]; int4 v; } u;
  u.s[0] = pack_bf16(a.x, a.y);
  u.s[1] = pack_bf16(a.z, a.w);
  u.s[2] = pack_bf16(b.x, b.y);
  u.s[3] = pack_bf16(b.z, b.w);
  *reinterpret_cast<int4*>(out + i) = u.v;
}

// ---------------------------------------------------------------------------
// W (fp32, K x N = 1024x1024) -> W^T (bf16, N x K). 64x64 LDS tile.
// ---------------------------------------------------------------------------
__global__ __launch_bounds__(256) void cvtT_bf16_kernel(const float* __restrict__ W,
                                                        __hip_bfloat16* __restrict__ WT) {
  __shared__ __hip_bfloat16 tile[64][66];
  const int w = threadIdx.x >> 6, l = threadIdx.x & 63;
  const int n0 = blockIdx.x * 64, k0 = blockIdx.y * 64;
#pragma unroll
  for (int r = 0; r < 16; ++r) {
    const int k = k0 + w * 16 + r;
    tile[w * 16 + r][l] = __float2bfloat16(W[(size_t)k * C_ + n0 + l]);
  }
  __syncthreads();
#pragma unroll
  for (int r = 0; r < 16; ++r) {
    const int nn = w * 16 + r;
    WT[(size_t)(n0 + nn) * C_ + k0 + l] = tile[l][nn];
  }
}

// ---------------------------------------------------------------------------
// MFMA GEMM: C[M,N](fp32) = A(bf16, M x K) @ BT(bf16, N x K)^T. m97 recipe.
// ---------------------------------------------------------------------------
__global__ __launch_bounds__(256) void gemm_mfma_kernel(const __hip_bfloat16* __restrict__ A,
                                                        const __hip_bfloat16* __restrict__ BT,
                                                        float* __restrict__ Cout,
                                                        int M, int N, int K) {
  __shared__ __hip_bfloat16 As[128 * 32];
  __shared__ __hip_bfloat16 Bs[128 * 32];
  const int tid = threadIdx.x;
  const int m0 = blockIdx.y * 128, n0 = blockIdx.x * 128;
  const int w = tid >> 6, l = tid & 63;
  const int n = l & 15, kg = l >> 4;
  const int m0w = (w & 1) * 64, n0w = (w >> 1) * 64;

  const int r0 = tid >> 2, o0 = (tid & 3) * 8;
  const __hip_bfloat16* ag0 = A + (size_t)(m0 + r0) * K + o0;
  const __hip_bfloat16* ag1 = A + (size_t)(m0 + 64 + r0) * K + o0;
  const __hip_bfloat16* bg0 = BT + (size_t)(n0 + r0) * K + o0;
  const __hip_bfloat16* bg1 = BT + (size_t)(n0 + 64 + r0) * K + o0;
  __hip_bfloat16* al0 = As + tid * 8;
  __hip_bfloat16* al1 = As + (256 + tid) * 8;
  __hip_bfloat16* bl0 = Bs + tid * 8;
  __hip_bfloat16* bl1 = Bs + (256 + tid) * 8;

  f32x4 acc[4][4];
#pragma unroll
  for (int i = 0; i < 4; ++i)
#pragma unroll
    for (int j = 0; j < 4; ++j) acc[i][j] = f32x4{0.f, 0.f, 0.f, 0.f};

  for (int k0 = 0; k0 < K; k0 += 32) {
    gl_lds16(ag0 + k0, al0);
    gl_lds16(ag1 + k0, al1);
    gl_lds16(bg0 + k0, bl0);
    gl_lds16(bg1 + k0, bl1);
    __syncthreads();
    bf16x8 af[4], bf[4];
#pragma unroll
    for (int ms = 0; ms < 4; ++ms)
      af[ms] = *reinterpret_cast<const bf16x8*>(As + (m0w + ms * 16 + n) * 32 + kg * 8);
#pragma unroll
    for (int ns = 0; ns < 4; ++ns)
      bf[ns] = *reinterpret_cast<const bf16x8*>(Bs + (n0w + ns * 16 + n) * 32 + kg * 8);
#pragma unroll
    for (int ms = 0; ms < 4; ++ms)
#pragma unroll
      for (int ns = 0; ns < 4; ++ns)
        acc[ms][ns] = __builtin_amdgcn_mfma_f32_16x16x32_bf16(af[ms], bf[ns], acc[ms][ns], 0, 0, 0);
    __syncthreads();
  }

#pragma unroll
  for (int ms = 0; ms < 4; ++ms) {
#pragma unroll
    for (int r = 0; r < 4; ++r) {
      const int row = m0 + m0w + ms * 16 + kg * 4 + r;
      float* cp = Cout + (size_t)row * N + n0 + n0w + n;
#pragma unroll
      for (int ns = 0; ns < 4; ++ns) cp[ns * 16] = acc[ms][ns][r];
    }
  }
}

// ---------------------------------------------------------------------------
// EMA pass 1: per-(bh,chunk) local scan (zero initial state).
// Writes local scans (fp32, (BH,T,HS)) + chunk-final vectors to carr.
// ---------------------------------------------------------------------------
__global__ __launch_bounds__(256) void ema_local_kernel(const float* __restrict__ xl,
                                                        float* __restrict__ loc,
                                                        float* __restrict__ carr,
                                                        const float* __restrict__ la_coef) {
  const int c = blockIdx.x % SCN_;
  const int bh = blockIdx.x / SCN_;
  const int b = bh / NH_, h = bh % NH_;
  const int tid = threadIdx.x;
  const int t0 = c * SCL_;
  __shared__ float buf[SCL_ * HS_];  // 32 KB

  const float alpha = la_coef[h];
  const float onema = 1.0f - alpha;
  const float4* src4 = reinterpret_cast<const float4*>(xl + (size_t)b * T_ * C_ + h * HS_);

  // stage: 2048 float4s; idx -> row tt=idx>>4, quad d4=idx&15. Coalesced 256B rows.
  float4* buf4 = reinterpret_cast<float4*>(buf);
#pragma unroll
  for (int i = 0; i < (SCL_ * HS_ / 4) / 256; ++i) {  // 8 iters
    const int idx = tid + i * 256;
    const int tt = idx >> 4, d4 = idx & 15;
    buf4[tt * 16 + d4] = src4[(size_t)(t0 + tt) * (C_ / 4) + d4];
  }
  __syncthreads();
  if (tid < 64) {
    const int d = tid;
    float c2 = 0.0f;
#pragma unroll 8
    for (int tt = 0; tt < SCL_; ++tt) {
      c2 = alpha * c2 + onema * buf[tt * HS_ + d];
      buf[tt * HS_ + d] = c2;
    }
    carr[(size_t)(bh * SCN_ + c) * HS_ + d] = c2;  // chunk-final
  }
  __syncthreads();
  // write local scan out, fully coalesced float4 (32KB contiguous)
  float4* dst4 = reinterpret_cast<float4*>(loc + ((size_t)bh * T_ + t0) * HS_);
#pragma unroll
  for (int i = 0; i < (SCL_ * HS_ / 4) / 256; ++i) dst4[tid + i * 256] = buf4[tid + i * 256];
}

// ---------------------------------------------------------------------------
// EMA pass 2: sequential carry combine per bh (in-place: finals -> incoming
// carries). A_0 = 0; A_{c+1} = alpha^L * A_c + final_c. 16 steps, trivial.
// ---------------------------------------------------------------------------
__global__ __launch_bounds__(64) void ema_carry_kernel(float* __restrict__ carr,
                                                       const float* __restrict__ la_coef) {
  const int bh = blockIdx.x;
  const int h = bh % NH_;
  const int d = threadIdx.x;
  const float alpha = la_coef[h];
  const float aL = __powf(alpha, (float)SCL_);
  float A = 0.0f;
  for (int c = 0; c < SCN_; ++c) {
    float* p = carr + (size_t)(bh * SCN_ + c) * HS_ + d;
    const float f = *p;
    *p = A;
    A = aL * A + f;
  }
}

// ---------------------------------------------------------------------------
// EMA pass 3: k_t = local_t + alpha^{tl+1} * A_c, row-normalize, kb-scale,
// emit bf16 k (BH,T,HS). 4 waves x 32 rows per block.
// ---------------------------------------------------------------------------
__global__ __launch_bounds__(256) void ema_fix_norm_kernel(const float* __restrict__ loc,
                                                           const float* __restrict__ carr,
                                                           __hip_bfloat16* __restrict__ kb16,
                                                           const float* __restrict__ la_coef,
                                                           const float* __restrict__ kernel_beta) {
  const int c = blockIdx.x % SCN_;
  const int bh = blockIdx.x / SCN_;
  const int h = bh % NH_;
  const int w = threadIdx.x >> 6, l = threadIdx.x & 63;

  const float alpha = la_coef[h];
  const float kbs = expf(fminf(kernel_beta[h] * 10.0f, 5.0f));
  const float A = carr[(size_t)(bh * SCN_ + c) * HS_ + l];
  const float* lp = loc + ((size_t)bh * T_ + c * SCL_ + w * 32) * HS_ + l;
  __hip_bfloat16* kp = kb16 + ((size_t)bh * T_ + c * SCL_ + w * 32) * HS_ + l;

  float s = __powf(alpha, (float)(w * 32 + 1));
  for (int rr = 0; rr < 32; ++rr) {
    float val = lp[rr * HS_] + s * A;
    float ss = val * val;
#pragma unroll
    for (int m = 32; m; m >>= 1) ss += __shfl_xor(ss, m);
    kp[rr * HS_] = __float2bfloat16(val * (kbs / sqrtf(ss)));
    s *= alpha;
  }
}

// ---------------------------------------------------------------------------
// Build v (shift-mix, normalize, scale), emit TILE-MAJOR transposed bf16
// vt (BH, T/64, HS, 64): each 64-key tile is 8KB contiguous for DMA staging.
// ---------------------------------------------------------------------------
__global__ __launch_bounds__(256) void vprep_kernel(const float* __restrict__ xv,
                                                    __hip_bfloat16* __restrict__ vt,
                                                    const float* __restrict__ value_beta,
                                                    const float* __restrict__ v_coef) {
  const int nchunk = T_ / 64;
  const int tc = blockIdx.x % nchunk;
  const int bh = blockIdx.x / nchunk;
  const int h = bh % NH_, b = bh / NH_;
  const int t0 = tc * 64;
  const int w = threadIdx.x >> 6, l = threadIdx.x & 63;
  __shared__ __hip_bfloat16 tile[64][66];

  const float c = v_coef[h];
  const float vb = expf(value_beta[h] * 10.0f);

  for (int r = 0; r < 16; ++r) {
    const int tl = w * 16 + r;
    const int t = t0 + tl;
    const float* base = xv + ((size_t)b * T_ + t) * C_ + h * HS_ + l;
    const float cur = base[0];
    const float nxt = (t + 1 < T_) ? base[C_] : 0.0f;
    float val = nxt * (1.0f - c) + cur * c;
    float ssum = val * val;
#pragma unroll
    for (int m = 32; m; m >>= 1) ssum += __shfl_xor(ssum, m);
    tile[tl][l] = __float2bfloat16(val * (vb / sqrtf(ssum)));
  }
  __syncthreads();
  __hip_bfloat16* vtb = vt + (((size_t)bh * nchunk + tc) * HS_) * 64;
  for (int rr = 0; rr < 16; ++rr) {
    const int hs = w * 16 + rr;
    vtb[(size_t)hs * 64 + l] = tile[l][hs];
  }
}

// ---------------------------------------------------------------------------
// MFMA flash attention, LDS-staged. Scores bounded by e^2 -> no online max.
// ---------------------------------------------------------------------------
__global__ __launch_bounds__(256) void attn_mfma_kernel(
    const __hip_bfloat16* __restrict__ kb,   // (BH, T, HS)
    const __hip_bfloat16* __restrict__ vt,   // (BH, T/64, HS, 64) tile-major
    __hip_bfloat16* __restrict__ y) {        // (B, T, C) bf16
  __shared__ __hip_bfloat16 Ks[64 * 64];     // [key][hs]
  __shared__ __hip_bfloat16 Vs[64 * 64];     // [hs][key]
  __shared__ __hip_bfloat16 Ps[4][16 * 68];  // per-wave P: [query][key], pad 68

  const int bh = blockIdx.y;
  const int b = bh / NH_, h = bh % NH_;
  const int qt = (T_ / 64 - 1) - (int)blockIdx.x;  // longest first
  const int q0 = qt * 64;
  const int w = threadIdx.x >> 6;
  const int l = threadIdx.x & 63;
  const int n = l & 15;
  const int kg = l >> 4;
  const int query = q0 + w * 16 + n;
  const int lo = l * 8;  // per-lane 16B offset (elements)

  const __hip_bfloat16* kbh = kb + (size_t)bh * (T_ * HS_);
  const __hip_bfloat16* vbh = vt + (size_t)bh * (T_ * HS_);

  bf16x8 qf0, qf1;
  {
    const __hip_bfloat16* qrow = kbh + (size_t)query * HS_ + kg * 8;
    qf0 = *reinterpret_cast<const bf16x8*>(qrow);
    qf1 = *reinterpret_cast<const bf16x8*>(qrow + 32);
  }

  f32x4 accO[4];
#pragma unroll
  for (int i = 0; i < 4; ++i) accO[i] = f32x4{0.f, 0.f, 0.f, 0.f};
  float l_acc = 0.0f;

  __hip_bfloat16* Pw = Ps[w];
  int* Pwi = reinterpret_cast<int*>(Pw);

  for (int jt = 0; jt <= qt; ++jt) {
    const int j0 = jt * 64;
    const bool diag = (jt == qt);

    {
      const __hip_bfloat16* kgp = kbh + (size_t)(j0 + w * 16) * HS_ + lo;
      __hip_bfloat16* kls = Ks + w * 16 * 64 + lo;
      gl_lds16(kgp, kls);
      gl_lds16(kgp + 512, kls + 512);
      const __hip_bfloat16* vgp = vbh + (size_t)jt * (64 * HS_) + (size_t)(w * 16) * 64 + lo;
      __hip_bfloat16* vls = Vs + w * 16 * 64 + lo;
      gl_lds16(vgp, vls);
      gl_lds16(vgp + 512, vls + 512);
    }
    __syncthreads();

    f32x4 accS[4];
#pragma unroll
    for (int ms = 0; ms < 4; ++ms) {
      const __hip_bfloat16* kr = Ks + (ms * 16 + n) * 64 + kg * 8;
      bf16x8 a0 = *reinterpret_cast<const bf16x8*>(kr);
      bf16x8 a1 = *reinterpret_cast<const bf16x8*>(kr + 32);
      f32x4 z{0.f, 0.f, 0.f, 0.f};
      z = __builtin_amdgcn_mfma_f32_16x16x32_bf16(a0, qf0, z, 0, 0, 0);
      accS[ms] = __builtin_amdgcn_mfma_f32_16x16x32_bf16(a1, qf1, z, 0, 0, 0);
    }

    float lsum = 0.0f;
    const int qq = w * 16 + n;
#pragma unroll
    for (int ms = 0; ms < 4; ++ms) {
      const int kbase = ms * 16 + kg * 4;
      float p[4];
#pragma unroll
      for (int r = 0; r < 4; ++r) {
        const float e = __expf(accS[ms][r]);
        p[r] = (!diag || (kbase + r < qq)) ? e : 0.0f;
        lsum += p[r];
      }
      const int po = n * 34 + ms * 8 + kg * 2;
      Pwi[po] = pack_bf16(p[0], p[1]);
      Pwi[po + 1] = pack_bf16(p[2], p[3]);
    }
    lsum += __shfl_xor(lsum, 16);
    lsum += __shfl_xor(lsum, 32);
    l_acc += lsum;

#pragma unroll
    for (int ks = 0; ks < 2; ++ks) {
      union { ushort4 u[2]; bf16x8 v; } pr;
      const __hip_bfloat16* pp = Pw + n * 68 + ks * 32 + kg * 8;
      pr.u[0] = *reinterpret_cast<const ushort4*>(pp);
      pr.u[1] = *reinterpret_cast<const ushort4*>(pp + 4);
#pragma unroll
      for (int mo = 0; mo < 4; ++mo) {
        const __hip_bfloat16* vr = Vs + (mo * 16 + n) * 64 + ks * 32 + kg * 8;
        bf16x8 av = *reinterpret_cast<const bf16x8*>(vr);
        accO[mo] = __builtin_amdgcn_mfma_f32_16x16x32_bf16(av, pr.v, accO[mo], 0, 0, 0);
      }
    }
    __syncthreads();
  }

  const float inv = (query == 0) ? 0.0f : 1.0f / l_acc;
  __hip_bfloat16* yb = y + ((size_t)b * T_ + query) * C_ + h * HS_;
#pragma unroll
  for (int mo = 0; mo < 4; ++mo) {
    int2 pkd;
    pkd.x = pack_bf16(accO[mo][0] * inv, accO[mo][1] * inv);
    pkd.y = pack_bf16(accO[mo][2] * inv, accO[mo][3] * inv);
    *reinterpret_cast<int2*>(yb + mo * 16 + kg * 4) = pkd;
  }
}

// ---------------------------------------------------------------------------
extern "C" void kernel_launch(void* const* d_in, const int* in_sizes, int n_in,
                              void* d_out, int out_size, void* d_ws, size_t ws_size,
                              hipStream_t stream) {
  const float* x           = (const float*)d_in[0];
  const float* W_la        = (const float*)d_in[1];
  const float* la_coef     = (const float*)d_in[2];
  const float* kernel_beta = (const float*)d_in[3];
  const float* value_beta  = (const float*)d_in[4];
  const float* W_v         = (const float*)d_in[5];
  const float* v_coef      = (const float*)d_in[6];
  const float* W_proj      = (const float*)d_in[7];
  float* out = (float*)d_out;

  char* wsb = (char*)d_ws;
  const size_t MB = 1024u * 1024u;
  __hip_bfloat16* x16    = (__hip_bfloat16*)(wsb);            // 8 MB
  __hip_bfloat16* WlaT   = (__hip_bfloat16*)(wsb + 8 * MB);   // 2 MB
  __hip_bfloat16* WvT    = (__hip_bfloat16*)(wsb + 10 * MB);  // 2 MB
  __hip_bfloat16* WprojT = (__hip_bfloat16*)(wsb + 12 * MB);  // 2 MB
  float* carr            = (float*)(wsb + 14 * MB);           // 128 KB (14..16MB gap)
  float* xl              = (float*)(wsb + 16 * MB);           // 16 MB
  float* xv              = (float*)(wsb + 32 * MB);           // 16 MB
  __hip_bfloat16* kb16   = (__hip_bfloat16*)(wsb + 48 * MB);  // 8 MB
  __hip_bfloat16* vt16   = (__hip_bfloat16*)(wsb + 56 * MB);  // 8 MB
  float* loc             = xv;                                 // reuse: xv dead after vprep
  __hip_bfloat16* y16    = (__hip_bfloat16*)(wsb + 16 * MB);  // aliases xl (dead after pass1)
  (void)ws_size; (void)in_sizes; (void)n_in; (void)out_size;

  const int M = B_ * T_;
  dim3 ggm(C_ / 128, M / 128);  // (8, 32)
  dim3 ggt(C_ / 64, C_ / 64);   // (16, 16)

  cvt_bf16_kernel<<<dim3((M * C_) / 2048), dim3(256), 0, stream>>>(x, x16);
  cvtT_bf16_kernel<<<ggt, dim3(256), 0, stream>>>(W_la, WlaT);
  cvtT_bf16_kernel<<<ggt, dim3(256), 0, stream>>>(W_v, WvT);
  cvtT_bf16_kernel<<<ggt, dim3(256), 0, stream>>>(W_proj, WprojT);

  gemm_mfma_kernel<<<ggm, dim3(256), 0, stream>>>(x16, WlaT, xl, M, C_, C_);
  gemm_mfma_kernel<<<ggm, dim3(256), 0, stream>>>(x16, WvT, xv, M, C_, C_);
  vprep_kernel<<<dim3(B_ * NH_ * (T_ / 64)), dim3(256), 0, stream>>>(xv, vt16, value_beta, v_coef);
  ema_local_kernel<<<dim3(B_ * NH_ * SCN_), dim3(256), 0, stream>>>(xl, loc, carr, la_coef);
  ema_carry_kernel<<<dim3(B_ * NH_), dim3(64), 0, stream>>>(carr, la_coef);
  ema_fix_norm_kernel<<<dim3(B_ * NH_ * SCN_), dim3(256), 0, stream>>>(loc, carr, kb16, la_coef, kernel_beta);
  attn_mfma_kernel<<<dim3(T_ / 64, B_ * NH_), dim3(256), 0, stream>>>(kb16, vt16, y16);
  gemm_mfma_kernel<<<ggm, dim3(256), 0, stream>>>(y16, WprojT, out, M, C_, C_);
}

// Round 8
// 250.171 us; speedup vs baseline: 20.0840x; 1.1948x over previous
//
#include <hip/hip_runtime.h>
#include <hip/hip_bf16.h>

#define B_  2
#define T_  2048
#define NH_ 16
#define HS_ 64
#define C_  1024
#define SCL_ 128              // EMA chunk length
#define SCN_ (T_ / SCL_)      // 16 chunks
#define NT_  (T_ / 64)        // 32 key/query tiles
#define TEL_ 4096             // elements per 64x64 tile

typedef __attribute__((ext_vector_type(8))) short bf16x8;
typedef __attribute__((ext_vector_type(4))) float f32x4;

__device__ inline int pack_bf16(float a, float b) {
  union { __hip_bfloat16 h; unsigned short u; } ua, ub;
  ua.h = __float2bfloat16(a);
  ub.h = __float2bfloat16(b);
  return (int)(((unsigned)ub.u << 16) | (unsigned)ua.u);
}

// async global->LDS 16B: global ptr is PER-LANE; LDS dest must equal
// wave-uniform base + lane*16. Callers pass per-lane g AND l = base+lane*16.
__device__ inline void gl_lds16(const __hip_bfloat16* g, __hip_bfloat16* l) {
  __builtin_amdgcn_global_load_lds(
      (const __attribute__((address_space(1))) unsigned int*)g,
      (__attribute__((address_space(3))) unsigned int*)l, 16, 0, 0);
}

// ---------------------------------------------------------------------------
// fp32 -> bf16 elementwise (8 elems/thread)
// ---------------------------------------------------------------------------
__global__ __launch_bounds__(256) void cvt_bf16_kernel(const float* __restrict__ in,
                                                       __hip_bfloat16* __restrict__ out) {
  const int i = (blockIdx.x * 256 + threadIdx.x) * 8;
  const float4 a = *reinterpret_cast<const float4*>(in + i);
  const float4 b = *reinterpret_cast<const float4*>(in + i + 4);
  union { int s[4]; int4 v; } u;
  u.s[0] = pack_bf16(a.x, a.y);
  u.s[1] = pack_bf16(a.z, a.w);
  u.s[2] = pack_bf16(b.x, b.y);
  u.s[3] = pack_bf16(b.z, b.w);
  *reinterpret_cast<int4*>(out + i) = u.v;
}

// ---------------------------------------------------------------------------
// All 3 weights (fp32 K x N) -> W^T (bf16 N x K) in one launch.
// z=0: W_la -> Wcat rows 0..1023; z=1: W_v -> Wcat rows 1024..2047; z=2: W_proj.
// ---------------------------------------------------------------------------
__global__ __launch_bounds__(256) void cvtT_all_kernel(const float* __restrict__ W_la,
                                                       const float* __restrict__ W_v,
                                                       const float* __restrict__ W_proj,
                                                       __hip_bfloat16* __restrict__ Wcat,
                                                       __hip_bfloat16* __restrict__ WprojT) {
  __shared__ __hip_bfloat16 tile[64][66];
  const int z = blockIdx.z;
  const float* W = (z == 0) ? W_la : (z == 1) ? W_v : W_proj;
  __hip_bfloat16* WT = (z == 2) ? WprojT : Wcat + (size_t)z * C_ * C_;
  const int w = threadIdx.x >> 6, l = threadIdx.x & 63;
  const int n0 = blockIdx.x * 64, k0 = blockIdx.y * 64;
#pragma unroll
  for (int r = 0; r < 16; ++r) {
    const int k = k0 + w * 16 + r;
    tile[w * 16 + r][l] = __float2bfloat16(W[(size_t)k * C_ + n0 + l]);
  }
  __syncthreads();
#pragma unroll
  for (int r = 0; r < 16; ++r) {
    const int nn = w * 16 + r;
    WT[(size_t)(n0 + nn) * C_ + k0 + l] = tile[l][nn];
  }
}

// ---------------------------------------------------------------------------
// Combined input GEMM: [xl | xv] = x16(4096x1024) @ Wcat(2048x1024)^T.
// 128x128 tile, BK=32, m97 recipe. Each block's n-range falls wholly in one
// of the two outputs. Grid (16, 32) = 512 blocks = 2/CU.
// ---------------------------------------------------------------------------
__global__ __launch_bounds__(256) void gemm_in_kernel(const __hip_bfloat16* __restrict__ A,
                                                      const __hip_bfloat16* __restrict__ BT,
                                                      float* __restrict__ C0,
                                                      float* __restrict__ C1) {
  __shared__ __hip_bfloat16 As[128 * 32];
  __shared__ __hip_bfloat16 Bs[128 * 32];
  const int tid = threadIdx.x;
  const int m0 = blockIdx.y * 128, n0 = blockIdx.x * 128;
  const int w = tid >> 6, l = tid & 63;
  const int n = l & 15, kg = l >> 4;
  const int m0w = (w & 1) * 64, n0w = (w >> 1) * 64;

  const int r0 = tid >> 2, o0 = (tid & 3) * 8;
  const __hip_bfloat16* ag0 = A + (size_t)(m0 + r0) * C_ + o0;
  const __hip_bfloat16* ag1 = A + (size_t)(m0 + 64 + r0) * C_ + o0;
  const __hip_bfloat16* bg0 = BT + (size_t)(n0 + r0) * C_ + o0;
  const __hip_bfloat16* bg1 = BT + (size_t)(n0 + 64 + r0) * C_ + o0;
  __hip_bfloat16* al0 = As + tid * 8;
  __hip_bfloat16* al1 = As + (256 + tid) * 8;
  __hip_bfloat16* bl0 = Bs + tid * 8;
  __hip_bfloat16* bl1 = Bs + (256 + tid) * 8;

  f32x4 acc[4][4];
#pragma unroll
  for (int i = 0; i < 4; ++i)
#pragma unroll
    for (int j = 0; j < 4; ++j) acc[i][j] = f32x4{0.f, 0.f, 0.f, 0.f};

  for (int k0 = 0; k0 < C_; k0 += 32) {
    gl_lds16(ag0 + k0, al0);
    gl_lds16(ag1 + k0, al1);
    gl_lds16(bg0 + k0, bl0);
    gl_lds16(bg1 + k0, bl1);
    __syncthreads();
    bf16x8 af[4], bf[4];
#pragma unroll
    for (int ms = 0; ms < 4; ++ms)
      af[ms] = *reinterpret_cast<const bf16x8*>(As + (m0w + ms * 16 + n) * 32 + kg * 8);
#pragma unroll
    for (int ns = 0; ns < 4; ++ns)
      bf[ns] = *reinterpret_cast<const bf16x8*>(Bs + (n0w + ns * 16 + n) * 32 + kg * 8);
#pragma unroll
    for (int ms = 0; ms < 4; ++ms)
#pragma unroll
      for (int ns = 0; ns < 4; ++ns)
        acc[ms][ns] = __builtin_amdgcn_mfma_f32_16x16x32_bf16(af[ms], bf[ns], acc[ms][ns], 0, 0, 0);
    __syncthreads();
  }

  float* Cb = (n0 < C_) ? C0 : C1;
  const int nc = (n0 < C_) ? n0 : n0 - C_;
#pragma unroll
  for (int ms = 0; ms < 4; ++ms) {
#pragma unroll
    for (int r = 0; r < 4; ++r) {
      const int row = m0 + m0w + ms * 16 + kg * 4 + r;
      float* cp = Cb + (size_t)row * C_ + nc + n0w + n;
#pragma unroll
      for (int ns = 0; ns < 4; ++ns) cp[ns * 16] = acc[ms][ns][r];
    }
  }
}

// ---------------------------------------------------------------------------
// Projection GEMM: out = y16(4096x1024) @ WprojT(1024x1024)^T, fp32 out.
// 64x128 tile -> grid (8, 64) = 512 blocks = 2/CU.
// ---------------------------------------------------------------------------
__global__ __launch_bounds__(256) void gemm_proj_kernel(const __hip_bfloat16* __restrict__ A,
                                                        const __hip_bfloat16* __restrict__ BT,
                                                        float* __restrict__ Cout) {
  __shared__ __hip_bfloat16 As[64 * 32];
  __shared__ __hip_bfloat16 Bs[128 * 32];
  const int tid = threadIdx.x;
  const int m0 = blockIdx.y * 64, n0 = blockIdx.x * 128;
  const int w = tid >> 6, l = tid & 63;
  const int n = l & 15, kg = l >> 4;

  const int r0 = tid >> 2, o0 = (tid & 3) * 8;
  const __hip_bfloat16* ag = A + (size_t)(m0 + r0) * C_ + o0;
  const __hip_bfloat16* bg0 = BT + (size_t)(n0 + r0) * C_ + o0;
  const __hip_bfloat16* bg1 = BT + (size_t)(n0 + 64 + r0) * C_ + o0;
  __hip_bfloat16* al = As + tid * 8;
  __hip_bfloat16* bl0 = Bs + tid * 8;
  __hip_bfloat16* bl1 = Bs + (256 + tid) * 8;

  f32x4 acc[4][2];
#pragma unroll
  for (int i = 0; i < 4; ++i)
#pragma unroll
    for (int j = 0; j < 2; ++j) acc[i][j] = f32x4{0.f, 0.f, 0.f, 0.f};

  for (int k0 = 0; k0 < C_; k0 += 32) {
    gl_lds16(ag + k0, al);
    gl_lds16(bg0 + k0, bl0);
    gl_lds16(bg1 + k0, bl1);
    __syncthreads();
    bf16x8 af[4], bf[2];
#pragma unroll
    for (int ms = 0; ms < 4; ++ms)
      af[ms] = *reinterpret_cast<const bf16x8*>(As + (ms * 16 + n) * 32 + kg * 8);
#pragma unroll
    for (int ns = 0; ns < 2; ++ns)
      bf[ns] = *reinterpret_cast<const bf16x8*>(Bs + (w * 32 + ns * 16 + n) * 32 + kg * 8);
#pragma unroll
    for (int ms = 0; ms < 4; ++ms)
#pragma unroll
      for (int ns = 0; ns < 2; ++ns)
        acc[ms][ns] = __builtin_amdgcn_mfma_f32_16x16x32_bf16(af[ms], bf[ns], acc[ms][ns], 0, 0, 0);
    __syncthreads();
  }

#pragma unroll
  for (int ms = 0; ms < 4; ++ms) {
#pragma unroll
    for (int r = 0; r < 4; ++r) {
      const int row = m0 + ms * 16 + kg * 4 + r;
      float* cp = Cout + (size_t)row * C_ + n0 + w * 32 + n;
#pragma unroll
      for (int ns = 0; ns < 2; ++ns) cp[ns * 16] = acc[ms][ns][r];
    }
  }
}

// ---------------------------------------------------------------------------
// EMA pass 1: per-(bh,chunk) local scan (zero initial state).
// Writes local scans (fp32, (BH,T,HS)) + chunk-final vectors to carr.
// ---------------------------------------------------------------------------
__global__ __launch_bounds__(256) void ema_local_kernel(const float* __restrict__ xl,
                                                        float* __restrict__ loc,
                                                        float* __restrict__ carr,
                                                        const float* __restrict__ la_coef) {
  const int c = blockIdx.x % SCN_;
  const int bh = blockIdx.x / SCN_;
  const int b = bh / NH_, h = bh % NH_;
  const int tid = threadIdx.x;
  const int t0 = c * SCL_;
  __shared__ float buf[SCL_ * HS_];  // 32 KB

  const float alpha = la_coef[h];
  const float onema = 1.0f - alpha;
  const float4* src4 = reinterpret_cast<const float4*>(xl + (size_t)b * T_ * C_ + h * HS_);

  float4* buf4 = reinterpret_cast<float4*>(buf);
#pragma unroll
  for (int i = 0; i < (SCL_ * HS_ / 4) / 256; ++i) {  // 8 iters
    const int idx = tid + i * 256;
    const int tt = idx >> 4, d4 = idx & 15;
    buf4[tt * 16 + d4] = src4[(size_t)(t0 + tt) * (C_ / 4) + d4];
  }
  __syncthreads();
  if (tid < 64) {
    const int d = tid;
    float c2 = 0.0f;
#pragma unroll 8
    for (int tt = 0; tt < SCL_; ++tt) {
      c2 = alpha * c2 + onema * buf[tt * HS_ + d];
      buf[tt * HS_ + d] = c2;
    }
    carr[(size_t)(bh * SCN_ + c) * HS_ + d] = c2;  // chunk-final
  }
  __syncthreads();
  float4* dst4 = reinterpret_cast<float4*>(loc + ((size_t)bh * T_ + t0) * HS_);
#pragma unroll
  for (int i = 0; i < (SCL_ * HS_ / 4) / 256; ++i) dst4[tid + i * 256] = buf4[tid + i * 256];
}

// ---------------------------------------------------------------------------
// EMA pass 2 (fused carry): k_t = local_t + alpha^{tl+1} * A_c where each
// block Horner-combines the <=15 earlier chunk-finals itself. Row-normalize,
// kb-scale, emit bf16 k in TILE-SLOT layout (BH, NT, g=hs>>3, key, 8).
// ---------------------------------------------------------------------------
__global__ __launch_bounds__(256) void ema_fix_norm_kernel(const float* __restrict__ loc,
                                                           const float* __restrict__ carr,
                                                           __hip_bfloat16* __restrict__ kb16,
                                                           const float* __restrict__ la_coef,
                                                           const float* __restrict__ kernel_beta) {
  const int c = blockIdx.x % SCN_;
  const int bh = blockIdx.x / SCN_;
  const int h = bh % NH_;
  const int w = threadIdx.x >> 6, l = threadIdx.x & 63;

  const float alpha = la_coef[h];
  const float aL = __powf(alpha, (float)SCL_);
  const float kbs = expf(fminf(kernel_beta[h] * 10.0f, 5.0f));

  float A = 0.0f;  // incoming state for this chunk (Horner over earlier finals)
  for (int cc = 0; cc < c; ++cc) A = aL * A + carr[(size_t)(bh * SCN_ + cc) * HS_ + l];

  const float* lp = loc + ((size_t)bh * T_ + c * SCL_ + w * 32) * HS_ + l;
  __hip_bfloat16* kt = kb16 + (size_t)bh * NT_ * TEL_;
  const int g = l >> 3, j = l & 7;

  float s = __powf(alpha, (float)(w * 32 + 1));
  for (int rr = 0; rr < 32; ++rr) {
    const int t = c * SCL_ + w * 32 + rr;
    float val = lp[rr * HS_] + s * A;
    float ss = val * val;
#pragma unroll
    for (int m = 32; m; m >>= 1) ss += __shfl_xor(ss, m);
    const int tile = t >> 6, key = t & 63;
    kt[(size_t)tile * TEL_ + (g * 64 + key) * 8 + j] = __float2bfloat16(val * (kbs / sqrtf(ss)));
    s *= alpha;
  }
}

// ---------------------------------------------------------------------------
// Build v (shift-mix, normalize, scale), emit TILE-SLOT bf16 vt
// (BH, NT, kk=key>>3, hs, 8): contiguous 8KB tiles, conflict-free frag reads.
// ---------------------------------------------------------------------------
__global__ __launch_bounds__(256) void vprep_kernel(const float* __restrict__ xv,
                                                    __hip_bfloat16* __restrict__ vt,
                                                    const float* __restrict__ value_beta,
                                                    const float* __restrict__ v_coef) {
  const int tc = blockIdx.x % NT_;
  const int bh = blockIdx.x / NT_;
  const int h = bh % NH_, b = bh / NH_;
  const int t0 = tc * 64;
  const int w = threadIdx.x >> 6, l = threadIdx.x & 63;
  __shared__ __hip_bfloat16 tile[64][66];

  const float c = v_coef[h];
  const float vb = expf(value_beta[h] * 10.0f);

  for (int r = 0; r < 16; ++r) {
    const int tl = w * 16 + r;
    const int t = t0 + tl;
    const float* base = xv + ((size_t)b * T_ + t) * C_ + h * HS_ + l;
    const float cur = base[0];
    const float nxt = (t + 1 < T_) ? base[C_] : 0.0f;
    float val = nxt * (1.0f - c) + cur * c;
    float ssum = val * val;
#pragma unroll
    for (int m = 32; m; m >>= 1) ssum += __shfl_xor(ssum, m);
    tile[tl][l] = __float2bfloat16(val * (vb / sqrtf(ssum)));
  }
  __syncthreads();
  __hip_bfloat16* vtb = vt + (size_t)(bh * NT_ + tc) * TEL_;
  const int kk = l >> 3, j = l & 7;  // l = key
  for (int rr = 0; rr < 16; ++rr) {
    const int hs = w * 16 + rr;
    vtb[(kk * 64 + hs) * 8 + j] = tile[l][hs];
  }
}

// ---------------------------------------------------------------------------
// MFMA flash attention, LDS-staged, slot-layout tiles (2-way-max conflicts),
// 128-key double-tile staging (half the barriers). No online max (|s|<=e^2).
// ---------------------------------------------------------------------------
__global__ __launch_bounds__(256) void attn_mfma_kernel(
    const __hip_bfloat16* __restrict__ kb,   // (BH, NT, g, key, 8) slot tiles
    const __hip_bfloat16* __restrict__ vt,   // (BH, NT, kk, hs, 8) slot tiles
    __hip_bfloat16* __restrict__ y) {        // (B, T, C) bf16
  __shared__ __hip_bfloat16 Ks[2][TEL_];
  __shared__ __hip_bfloat16 Vs[2][TEL_];
  __shared__ __hip_bfloat16 Ps[4][16 * 68];  // per-wave P: [query][key], pad 68

  const int bh = blockIdx.y;
  const int b = bh / NH_, h = bh % NH_;
  const int qt = (NT_ - 1) - (int)blockIdx.x;  // longest first
  const int q0 = qt * 64;
  const int w = threadIdx.x >> 6;
  const int l = threadIdx.x & 63;
  const int n = l & 15;
  const int kg = l >> 4;
  const int query = q0 + w * 16 + n;
  const int lo = l * 8;  // per-lane 16B offset (elements)
  const int tb = bh * NT_;

  // Q B-fragments from global slot tile (once)
  bf16x8 qf0, qf1;
  {
    const __hip_bfloat16* qtile = kb + (size_t)(tb + qt) * TEL_;
    qf0 = *reinterpret_cast<const bf16x8*>(qtile + (kg * 64 + w * 16 + n) * 8);
    qf1 = *reinterpret_cast<const bf16x8*>(qtile + ((kg + 4) * 64 + w * 16 + n) * 8);
  }

  f32x4 accO[4];
#pragma unroll
  for (int i = 0; i < 4; ++i) accO[i] = f32x4{0.f, 0.f, 0.f, 0.f};
  float l_acc = 0.0f;

  __hip_bfloat16* Pw = Ps[w];
  int* Pwi = reinterpret_cast<int*>(Pw);
  const int npair = (qt >> 1) + 1;

  for (int jp = 0; jp < npair; ++jp) {
    const int jt0 = jp * 2;
    const int nsub = (jt0 + 1 <= qt) ? 2 : 1;

    // ---- stage: contiguous 8KB copies per tile (K and V) ----
    for (int s = 0; s < nsub; ++s) {
      const size_t tbase = (size_t)(tb + jt0 + s) * TEL_;
      const __hip_bfloat16* kgp = kb + tbase + w * 1024 + lo;
      gl_lds16(kgp, &Ks[s][w * 1024 + lo]);
      gl_lds16(kgp + 512, &Ks[s][w * 1024 + 512 + lo]);
      const __hip_bfloat16* vgp = vt + tbase + w * 1024 + lo;
      gl_lds16(vgp, &Vs[s][w * 1024 + lo]);
      gl_lds16(vgp + 512, &Vs[s][w * 1024 + 512 + lo]);
    }
    __syncthreads();

    for (int s = 0; s < nsub; ++s) {
      const int jts = jt0 + s;
      const bool diag = (jts == qt);
      const __hip_bfloat16* Kss = Ks[s];
      const __hip_bfloat16* Vss = Vs[s];

      // ---- S^T = K @ Q^T (slot reads: bank = key*4 % 32, 2-way) ----
      f32x4 accS[4];
#pragma unroll
      for (int ms = 0; ms < 4; ++ms) {
        bf16x8 a0 = *reinterpret_cast<const bf16x8*>(Kss + (kg * 64 + ms * 16 + n) * 8);
        bf16x8 a1 = *reinterpret_cast<const bf16x8*>(Kss + ((kg + 4) * 64 + ms * 16 + n) * 8);
        f32x4 z{0.f, 0.f, 0.f, 0.f};
        z = __builtin_amdgcn_mfma_f32_16x16x32_bf16(a0, qf0, z, 0, 0, 0);
        accS[ms] = __builtin_amdgcn_mfma_f32_16x16x32_bf16(a1, qf1, z, 0, 0, 0);
      }

      // ---- exp + causal mask + row-sum; P to wave-local LDS ----
      float lsum = 0.0f;
      const int qq = w * 16 + n;
#pragma unroll
      for (int ms = 0; ms < 4; ++ms) {
        const int kbase = ms * 16 + kg * 4;
        float p[4];
#pragma unroll
        for (int r = 0; r < 4; ++r) {
          const float e = __expf(accS[ms][r]);
          p[r] = (!diag || (kbase + r < qq)) ? e : 0.0f;
          lsum += p[r];
        }
        const int po = n * 34 + ms * 8 + kg * 2;
        Pwi[po] = pack_bf16(p[0], p[1]);
        Pwi[po + 1] = pack_bf16(p[2], p[3]);
      }
      lsum += __shfl_xor(lsum, 16);
      lsum += __shfl_xor(lsum, 32);
      l_acc += lsum;

      // ---- O^T += V^T @ P^T ----
#pragma unroll
      for (int ks = 0; ks < 2; ++ks) {
        union { ushort4 u[2]; bf16x8 v; } pr;
        const __hip_bfloat16* pp = Pw + n * 68 + ks * 32 + kg * 8;
        pr.u[0] = *reinterpret_cast<const ushort4*>(pp);
        pr.u[1] = *reinterpret_cast<const ushort4*>(pp + 4);
#pragma unroll
        for (int mo = 0; mo < 4; ++mo) {
          bf16x8 av = *reinterpret_cast<const bf16x8*>(Vss + ((ks * 4 + kg) * 64 + mo * 16 + n) * 8);
          accO[mo] = __builtin_amdgcn_mfma_f32_16x16x32_bf16(av, pr.v, accO[mo], 0, 0, 0);
        }
      }
    }
    __syncthreads();
  }

  const float inv = (query == 0) ? 0.0f : 1.0f / l_acc;
  __hip_bfloat16* yb = y + ((size_t)b * T_ + query) * C_ + h * HS_;
#pragma unroll
  for (int mo = 0; mo < 4; ++mo) {
    int2 pkd;
    pkd.x = pack_bf16(accO[mo][0] * inv, accO[mo][1] * inv);
    pkd.y = pack_bf16(accO[mo][2] * inv, accO[mo][3] * inv);
    *reinterpret_cast<int2*>(yb + mo * 16 + kg * 4) = pkd;
  }
}

// ---------------------------------------------------------------------------
extern "C" void kernel_launch(void* const* d_in, const int* in_sizes, int n_in,
                              void* d_out, int out_size, void* d_ws, size_t ws_size,
                              hipStream_t stream) {
  const float* x           = (const float*)d_in[0];
  const float* W_la        = (const float*)d_in[1];
  const float* la_coef     = (const float*)d_in[2];
  const float* kernel_beta = (const float*)d_in[3];
  const float* value_beta  = (const float*)d_in[4];
  const float* W_v         = (const float*)d_in[5];
  const float* v_coef      = (const float*)d_in[6];
  const float* W_proj      = (const float*)d_in[7];
  float* out = (float*)d_out;

  char* wsb = (char*)d_ws;
  const size_t MB = 1024u * 1024u;
  __hip_bfloat16* x16    = (__hip_bfloat16*)(wsb);            // 8 MB
  __hip_bfloat16* Wcat   = (__hip_bfloat16*)(wsb + 8 * MB);   // 4 MB (W_laT | W_vT)
  __hip_bfloat16* WprojT = (__hip_bfloat16*)(wsb + 12 * MB);  // 2 MB
  float* carr            = (float*)(wsb + 14 * MB);           // 128 KB
  float* xl              = (float*)(wsb + 16 * MB);           // 16 MB
  float* xv              = (float*)(wsb + 32 * MB);           // 16 MB
  __hip_bfloat16* kb16   = (__hip_bfloat16*)(wsb + 48 * MB);  // 8 MB
  __hip_bfloat16* vt16   = (__hip_bfloat16*)(wsb + 56 * MB);  // 8 MB
  float* loc             = xv;                                 // reuse: xv dead after vprep
  __hip_bfloat16* y16    = (__hip_bfloat16*)(wsb + 16 * MB);  // aliases xl (dead after pass1)
  (void)ws_size; (void)in_sizes; (void)n_in; (void)out_size;

  const int M = B_ * T_;

  cvt_bf16_kernel<<<dim3((M * C_) / 2048), dim3(256), 0, stream>>>(x, x16);
  cvtT_all_kernel<<<dim3(C_ / 64, C_ / 64, 3), dim3(256), 0, stream>>>(W_la, W_v, W_proj, Wcat, WprojT);

  gemm_in_kernel<<<dim3(2 * C_ / 128, M / 128), dim3(256), 0, stream>>>(x16, Wcat, xl, xv);
  vprep_kernel<<<dim3(B_ * NH_ * NT_), dim3(256), 0, stream>>>(xv, vt16, value_beta, v_coef);
  ema_local_kernel<<<dim3(B_ * NH_ * SCN_), dim3(256), 0, stream>>>(xl, loc, carr, la_coef);
  ema_fix_norm_kernel<<<dim3(B_ * NH_ * SCN_), dim3(256), 0, stream>>>(loc, carr, kb16, la_coef, kernel_beta);
  attn_mfma_kernel<<<dim3(NT_, B_ * NH_), dim3(256), 0, stream>>>(kb16, vt16, y16);
  gemm_proj_kernel<<<dim3(C_ / 128, M / 64), dim3(256), 0, stream>>>(y16, WprojT, out);
}